// Round 1
// baseline (3963.594 us; speedup 1.0000x reference)
//
#include <hip/hip_runtime.h>
#include <hip/hip_bf16.h>
#include <cstddef>

// Problem constants (B=2, Lq=1024, Lkv=2048, D=1024, H=16, hd=64)
#define D_MODEL 1024
#define HEADS   16
#define HDIM    64

// ---------------------------------------------------------------------------
// zero kernel (attn-mean output region must start at 0; harness poisons 0xAA)
// ---------------------------------------------------------------------------
__global__ __launch_bounds__(256) void zero_f32(float* __restrict__ p, size_t n4) {
    size_t i = (size_t)blockIdx.x * 256 + threadIdx.x;
    if (i < n4) {
        ((float4*)p)[i] = make_float4(0.f, 0.f, 0.f, 0.f);
    }
}

// ---------------------------------------------------------------------------
// f32 tiled GEMM:  Y[r][n] = sum_k (X[r][k] + tok[k]) * W[n][k] + bias[n]
// tile 128x128, TK=16, 256 threads, 8x8 per thread.
// qkv==1: store into [b][h][L][64] head layout (L = 1<<Lshift), else flat.
// ---------------------------------------------------------------------------
#define TS 128
#define TK 16

__global__ __launch_bounds__(256)
void gemm_proj(const float* __restrict__ X, const float* __restrict__ tok,
               const float* __restrict__ W, const float* __restrict__ bias,
               float* __restrict__ Y, int Lshift, int qkv)
{
    __shared__ float As[TK][TS + 4];
    __shared__ float Bs[TK][TS + 4];
    const int tid = threadIdx.x;
    const int tx = tid & 15, ty = tid >> 4;
    const int m0 = blockIdx.y * TS, n0 = blockIdx.x * TS;
    const int lk = tid & 15;   // k within tile
    const int lm = tid >> 4;   // row step base

    float acc[8][8];
#pragma unroll
    for (int i = 0; i < 8; ++i)
#pragma unroll
        for (int j = 0; j < 8; ++j) acc[i][j] = 0.f;

    for (int k0 = 0; k0 < D_MODEL; k0 += TK) {
        float t = tok ? tok[k0 + lk] : 0.f;
#pragma unroll
        for (int j = 0; j < 8; ++j) {
            int m = lm + j * 16;
            As[lk][m] = X[(size_t)(m0 + m) * D_MODEL + k0 + lk] + t;
            Bs[lk][m] = W[(size_t)(n0 + m) * D_MODEL + k0 + lk];
        }
        __syncthreads();
#pragma unroll
        for (int kk = 0; kk < TK; ++kk) {
            float a[8], bv[8];
#pragma unroll
            for (int i = 0; i < 8; ++i) a[i] = As[kk][ty * 8 + i];
#pragma unroll
            for (int j = 0; j < 8; ++j) bv[j] = Bs[kk][tx * 8 + j];
#pragma unroll
            for (int i = 0; i < 8; ++i)
#pragma unroll
                for (int j = 0; j < 8; ++j) acc[i][j] += a[i] * bv[j];
        }
        __syncthreads();
    }

#pragma unroll
    for (int i = 0; i < 8; ++i) {
        int r = m0 + ty * 8 + i;
#pragma unroll
        for (int j = 0; j < 8; ++j) {
            int n = n0 + tx * 8 + j;
            float v = acc[i][j] + bias[n];
            if (qkv) {
                int b = r >> Lshift;
                int l = r & ((1 << Lshift) - 1);
                int h = n >> 6, d = n & 63;
                Y[((((size_t)b * HEADS + h) << Lshift) + l) * HDIM + d] = v;
            } else {
                Y[(size_t)r * D_MODEL + n] = v;
            }
        }
    }
}

// ---------------------------------------------------------------------------
// Attention pass 1: per-row running max m and sum l of exp(s - m).
// Block = 64 threads (1 wave) per (b, h, 64 q-rows). Each lane owns one q row.
// ---------------------------------------------------------------------------
__global__ __launch_bounds__(64)
void attn_pass1(const float* __restrict__ q, const float* __restrict__ k,
                float* __restrict__ mOut, float* __restrict__ linvOut)
{
    __shared__ float Ks[64 * 64];
    const int t = threadIdx.x;
    const int q0 = blockIdx.x * 64;
    const int h = blockIdx.y, b = blockIdx.z;

    const float* qrow = q + ((((size_t)b * HEADS + h) * 1024) + q0 + t) * HDIM;
    float qr[64];
#pragma unroll
    for (int i = 0; i < 64; i += 4) {
        float4 v4 = *(const float4*)(qrow + i);
        qr[i] = v4.x * 0.125f; qr[i + 1] = v4.y * 0.125f;
        qr[i + 2] = v4.z * 0.125f; qr[i + 3] = v4.w * 0.125f;
    }

    float m = -1e30f, l = 0.f;
    const float* kbase = k + ((size_t)b * HEADS + h) * 2048 * HDIM;

    for (int kv0 = 0; kv0 < 2048; kv0 += 64) {
        const float4* src = (const float4*)(kbase + (size_t)kv0 * HDIM);
        float4* dst = (float4*)Ks;
#pragma unroll
        for (int it = 0; it < 16; ++it) dst[it * 64 + t] = src[it * 64 + t];
        __syncthreads();

        for (int j = 0; j < 64; ++j) {
            const float* kr = Ks + j * 64;
            float s = 0.f;
#pragma unroll
            for (int d = 0; d < 64; d += 4) {
                float4 kv4 = *(const float4*)(kr + d);
                s += qr[d] * kv4.x + qr[d + 1] * kv4.y + qr[d + 2] * kv4.z + qr[d + 3] * kv4.w;
            }
            float mn = fmaxf(m, s);
            l = l * __expf(m - mn) + __expf(s - mn);
            m = mn;
        }
        __syncthreads();
    }
    size_t idx = (((size_t)b * HEADS + h) * 1024) + q0 + t;
    mOut[idx] = m;
    linvOut[idx] = 1.f / l;
}

// ---------------------------------------------------------------------------
// Attention pass 2: recompute s, p = exp(s-m)*linv; ctx += p*v; attn-mean via
// coalesced atomics (transpose p through LDS first).
// ---------------------------------------------------------------------------
__global__ __launch_bounds__(64)
void attn_pass2(const float* __restrict__ q, const float* __restrict__ k,
                const float* __restrict__ v,
                const float* __restrict__ mIn, const float* __restrict__ linvIn,
                float* __restrict__ ctxOut,   // [B][Lq][D]  (b, l, h*64+d)
                float* __restrict__ attnOut)  // [B][1024][2048]
{
    __shared__ float Ks[64 * 64];
    __shared__ float Vs[64 * 64];
    __shared__ float Ps[64][65];
    const int t = threadIdx.x;
    const int q0 = blockIdx.x * 64;
    const int h = blockIdx.y, b = blockIdx.z;

    const float* qrow = q + ((((size_t)b * HEADS + h) * 1024) + q0 + t) * HDIM;
    float qr[64];
#pragma unroll
    for (int i = 0; i < 64; i += 4) {
        float4 v4 = *(const float4*)(qrow + i);
        qr[i] = v4.x * 0.125f; qr[i + 1] = v4.y * 0.125f;
        qr[i + 2] = v4.z * 0.125f; qr[i + 3] = v4.w * 0.125f;
    }
    size_t idx = (((size_t)b * HEADS + h) * 1024) + q0 + t;
    const float m = mIn[idx];
    const float linv = linvIn[idx];

    float ctx[64];
#pragma unroll
    for (int i = 0; i < 64; ++i) ctx[i] = 0.f;

    const float* kbase = k + ((size_t)b * HEADS + h) * 2048 * HDIM;
    const float* vbase = v + ((size_t)b * HEADS + h) * 2048 * HDIM;

    for (int kv0 = 0; kv0 < 2048; kv0 += 64) {
        {
            const float4* srck = (const float4*)(kbase + (size_t)kv0 * HDIM);
            const float4* srcv = (const float4*)(vbase + (size_t)kv0 * HDIM);
            float4* dstk = (float4*)Ks;
            float4* dstv = (float4*)Vs;
#pragma unroll
            for (int it = 0; it < 16; ++it) {
                dstk[it * 64 + t] = srck[it * 64 + t];
                dstv[it * 64 + t] = srcv[it * 64 + t];
            }
        }
        __syncthreads();

        for (int j = 0; j < 64; ++j) {
            const float* kr = Ks + j * 64;
            float s = 0.f;
#pragma unroll
            for (int d = 0; d < 64; d += 4) {
                float4 kv4 = *(const float4*)(kr + d);
                s += qr[d] * kv4.x + qr[d + 1] * kv4.y + qr[d + 2] * kv4.z + qr[d + 3] * kv4.w;
            }
            float p = __expf(s - m) * linv;
            Ps[j][t] = p;
            const float* vr = Vs + j * 64;
#pragma unroll
            for (int d = 0; d < 64; d += 4) {
                float4 vv4 = *(const float4*)(vr + d);
                ctx[d]     += p * vv4.x;
                ctx[d + 1] += p * vv4.y;
                ctx[d + 2] += p * vv4.z;
                ctx[d + 3] += p * vv4.w;
            }
        }
        __syncthreads();

        // coalesced atomic accumulation of mean attn: lane t handles col kv0+t
        float* arow = attnOut + ((size_t)b * 1024 + q0) * 2048 + kv0;
#pragma unroll 8
        for (int r = 0; r < 64; ++r) {
            atomicAdd(arow + (size_t)r * 2048 + t, Ps[t][r] * 0.0625f);
        }
        __syncthreads();
    }

    // store ctx row: ctxOut[b][q0+t][h*64 + d]
    float* crow = ctxOut + ((size_t)b * 1024 + q0 + t) * D_MODEL + h * HDIM;
#pragma unroll
    for (int d = 0; d < 64; d += 4) {
        *(float4*)(crow + d) = make_float4(ctx[d], ctx[d + 1], ctx[d + 2], ctx[d + 3]);
    }
}

// ---------------------------------------------------------------------------
// launch
// ---------------------------------------------------------------------------
extern "C" void kernel_launch(void* const* d_in, const int* in_sizes, int n_in,
                              void* d_out, int out_size, void* d_ws, size_t ws_size,
                              hipStream_t stream)
{
    const float* x_cond  = (const float*)d_in[0];  // [2,2048,1024]
    const float* x_query = (const float*)d_in[1];  // [2,1024,1024]
    const float* tok     = (const float*)d_in[2];  // [2,1024]
    const float* w_in    = (const float*)d_in[3];  // [3072,1024]
    const float* b_in    = (const float*)d_in[4];  // [3072]
    const float* w_out   = (const float*)d_in[5];  // [1024,1024]
    const float* b_out   = (const float*)d_in[6];  // [1024]

    float* out   = (float*)d_out;
    float* fused = out;                    // 2*1024*1024
    float* attn  = out + 2097152;          // 2*1024*2048

    float* ws  = (float*)d_ws;
    float* q   = ws;                       // 2*16*1024*64 = 2,097,152
    float* k   = q + 2097152;              // 2*16*2048*64 = 4,194,304
    float* v   = k + 4194304;              // 4,194,304
    float* ctx = v + 4194304;              // 2,097,152
    float* mb  = ctx + 2097152;            // 32,768
    float* lb  = mb + 32768;               // 32,768

    // 1. zero attn-mean region (4,194,304 f32 = 1,048,576 float4)
    zero_f32<<<4096, 256, 0, stream>>>(attn, 1048576);

    // 2. projections (tok row 0 -> cond/K/V, row 1 -> query/Q)
    gemm_proj<<<dim3(8, 16), 256, 0, stream>>>(x_query, tok + D_MODEL, w_in, b_in, q, 10, 1);
    gemm_proj<<<dim3(8, 32), 256, 0, stream>>>(x_cond, tok, w_in + 1024 * 1024, b_in + 1024, k, 11, 1);
    gemm_proj<<<dim3(8, 32), 256, 0, stream>>>(x_cond, tok, w_in + 2 * 1024 * 1024, b_in + 2048, v, 11, 1);

    // 3. attention
    attn_pass1<<<dim3(16, 16, 2), 64, 0, stream>>>(q, k, mb, lb);
    attn_pass2<<<dim3(16, 16, 2), 64, 0, stream>>>(q, k, v, mb, lb, ctx, attn);

    // 4. output projection
    gemm_proj<<<dim3(8, 16), 256, 0, stream>>>(ctx, nullptr, w_out, b_out, fused, 0, 0);
}

// Round 3
// 1455.880 us; speedup vs baseline: 2.7225x; 2.7225x over previous
//
#include <hip/hip_runtime.h>
#include <hip/hip_bf16.h>
#include <cstddef>

// Problem constants (B=2, Lq=1024, Lkv=2048, D=1024, H=16, hd=64)
#define D_MODEL 1024
#define HEADS   16
#define HDIM    64

// ---------------------------------------------------------------------------
// f32 tiled GEMM:  Y[r][n] = sum_k (X[r][k] + tok[k]) * W[n][k] + bias[n]
// tile 128x128, TK=16, 256 threads, 8x8 per thread.
// qkv==1: store into [b][h][L][64] head layout (L = 1<<Lshift), else flat.
// ---------------------------------------------------------------------------
#define TS 128
#define TK 16

__global__ __launch_bounds__(256)
void gemm_proj(const float* __restrict__ X, const float* __restrict__ tok,
               const float* __restrict__ W, const float* __restrict__ bias,
               float* __restrict__ Y, int Lshift, int qkv)
{
    __shared__ float As[TK][TS + 4];
    __shared__ float Bs[TK][TS + 4];
    const int tid = threadIdx.x;
    const int tx = tid & 15, ty = tid >> 4;
    const int m0 = blockIdx.y * TS, n0 = blockIdx.x * TS;
    const int lk = tid & 15;   // k within tile
    const int lm = tid >> 4;   // row step base

    float acc[8][8];
#pragma unroll
    for (int i = 0; i < 8; ++i)
#pragma unroll
        for (int j = 0; j < 8; ++j) acc[i][j] = 0.f;

    for (int k0 = 0; k0 < D_MODEL; k0 += TK) {
        float t = tok ? tok[k0 + lk] : 0.f;
#pragma unroll
        for (int j = 0; j < 8; ++j) {
            int m = lm + j * 16;
            As[lk][m] = X[(size_t)(m0 + m) * D_MODEL + k0 + lk] + t;
            Bs[lk][m] = W[(size_t)(n0 + m) * D_MODEL + k0 + lk];
        }
        __syncthreads();
#pragma unroll
        for (int kk = 0; kk < TK; ++kk) {
            float a[8], bv[8];
#pragma unroll
            for (int i = 0; i < 8; ++i) a[i] = As[kk][ty * 8 + i];
#pragma unroll
            for (int j = 0; j < 8; ++j) bv[j] = Bs[kk][tx * 8 + j];
#pragma unroll
            for (int i = 0; i < 8; ++i)
#pragma unroll
                for (int j = 0; j < 8; ++j) acc[i][j] += a[i] * bv[j];
        }
        __syncthreads();
    }

#pragma unroll
    for (int i = 0; i < 8; ++i) {
        int r = m0 + ty * 8 + i;
#pragma unroll
        for (int j = 0; j < 8; ++j) {
            int n = n0 + tx * 8 + j;
            float v = acc[i][j] + bias[n];
            if (qkv) {
                int b = r >> Lshift;
                int l = r & ((1 << Lshift) - 1);
                int h = n >> 6, d = n & 63;
                Y[((((size_t)b * HEADS + h) << Lshift) + l) * HDIM + d] = v;
            } else {
                Y[(size_t)r * D_MODEL + n] = v;
            }
        }
    }
}

// ---------------------------------------------------------------------------
// Attention pass 1 (kv-chunked): per-row running max m and sum l over this
// chunk. Grid: (qtile + 16*chunk, h, b), block = 1 wave, lane = q row.
// ---------------------------------------------------------------------------
__global__ __launch_bounds__(64)
void attn_ml(const float* __restrict__ q, const float* __restrict__ k,
             float* __restrict__ pm, float* __restrict__ pl, int kvc)
{
    __shared__ float Ks[32 * 64];
    const int t = threadIdx.x;
    const int qt = blockIdx.x & 15, c = blockIdx.x >> 4;
    const int h = blockIdx.y, b = blockIdx.z;
    const int q0 = qt * 64;

    const float* qrow = q + ((((size_t)b * HEADS + h) * 1024) + q0 + t) * HDIM;
    float qr[64];
#pragma unroll
    for (int i = 0; i < 64; i += 4) {
        float4 v4 = *(const float4*)(qrow + i);
        qr[i] = v4.x * 0.125f; qr[i + 1] = v4.y * 0.125f;
        qr[i + 2] = v4.z * 0.125f; qr[i + 3] = v4.w * 0.125f;
    }

    float m = -1e30f, l = 0.f;
    const float* kbase = k + ((size_t)b * HEADS + h) * 2048 * HDIM + (size_t)c * kvc * HDIM;

    for (int kv0 = 0; kv0 < kvc; kv0 += 32) {
        __syncthreads();
        const float4* src = (const float4*)(kbase + (size_t)kv0 * HDIM);
        float4* dst = (float4*)Ks;
#pragma unroll
        for (int it = 0; it < 8; ++it) dst[it * 64 + t] = src[it * 64 + t];
        __syncthreads();

        for (int j = 0; j < 32; j += 4) {
            const float* k0 = Ks + j * 64;
            float s0 = 0.f, s1 = 0.f, s2 = 0.f, s3 = 0.f;
#pragma unroll
            for (int d = 0; d < 64; d += 4) {
                float4 a0 = *(const float4*)(k0 + d);
                float4 a1 = *(const float4*)(k0 + 64 + d);
                float4 a2 = *(const float4*)(k0 + 128 + d);
                float4 a3 = *(const float4*)(k0 + 192 + d);
                s0 += qr[d] * a0.x + qr[d + 1] * a0.y + qr[d + 2] * a0.z + qr[d + 3] * a0.w;
                s1 += qr[d] * a1.x + qr[d + 1] * a1.y + qr[d + 2] * a1.z + qr[d + 3] * a1.w;
                s2 += qr[d] * a2.x + qr[d + 1] * a2.y + qr[d + 2] * a2.z + qr[d + 3] * a2.w;
                s3 += qr[d] * a3.x + qr[d + 1] * a3.y + qr[d + 2] * a3.z + qr[d + 3] * a3.w;
            }
            float mn = fmaxf(m, fmaxf(fmaxf(s0, s1), fmaxf(s2, s3)));
            l = l * __expf(m - mn)
              + __expf(s0 - mn) + __expf(s1 - mn) + __expf(s2 - mn) + __expf(s3 - mn);
            m = mn;
        }
    }
    size_t row = (((size_t)b * HEADS + h) * 1024) + q0 + t;
    pm[(size_t)c * 32768 + row] = m;
    pl[(size_t)c * 32768 + row] = l;
}

// ---------------------------------------------------------------------------
// combine chunk (m,l) -> global m, 1/l
// ---------------------------------------------------------------------------
__global__ __launch_bounds__(256)
void combine_ml(const float* __restrict__ pm, const float* __restrict__ pl,
                float* __restrict__ m, float* __restrict__ linv, int C)
{
    int r = blockIdx.x * 256 + threadIdx.x;   // 32768 rows
    float mm = -1e30f;
    for (int c = 0; c < C; ++c) mm = fmaxf(mm, pm[(size_t)c * 32768 + r]);
    float l = 0.f;
    for (int c = 0; c < C; ++c)
        l += pl[(size_t)c * 32768 + r] * __expf(pm[(size_t)c * 32768 + r] - mm);
    m[r] = mm;
    linv[r] = 1.f / l;
}

// ---------------------------------------------------------------------------
// Attention pass 2 (kv-chunked): partial ctx with known (m, 1/l).
// ---------------------------------------------------------------------------
__global__ __launch_bounds__(64)
void attn_pv(const float* __restrict__ q, const float* __restrict__ k,
             const float* __restrict__ v,
             const float* __restrict__ mIn, const float* __restrict__ linvIn,
             float* __restrict__ pctx, int kvc)
{
    __shared__ float Ks[32 * 64];
    __shared__ float Vs[32 * 64];
    const int t = threadIdx.x;
    const int qt = blockIdx.x & 15, c = blockIdx.x >> 4;
    const int h = blockIdx.y, b = blockIdx.z;
    const int q0 = qt * 64;

    const float* qrow = q + ((((size_t)b * HEADS + h) * 1024) + q0 + t) * HDIM;
    float qr[64];
#pragma unroll
    for (int i = 0; i < 64; i += 4) {
        float4 v4 = *(const float4*)(qrow + i);
        qr[i] = v4.x * 0.125f; qr[i + 1] = v4.y * 0.125f;
        qr[i + 2] = v4.z * 0.125f; qr[i + 3] = v4.w * 0.125f;
    }
    size_t row = (((size_t)b * HEADS + h) * 1024) + q0 + t;
    const float m = mIn[row];
    const float linv = linvIn[row];

    float ctx[64];
#pragma unroll
    for (int i = 0; i < 64; ++i) ctx[i] = 0.f;

    const float* kbase = k + ((size_t)b * HEADS + h) * 2048 * HDIM + (size_t)c * kvc * HDIM;
    const float* vbase = v + ((size_t)b * HEADS + h) * 2048 * HDIM + (size_t)c * kvc * HDIM;

    for (int kv0 = 0; kv0 < kvc; kv0 += 32) {
        __syncthreads();
        {
            const float4* srck = (const float4*)(kbase + (size_t)kv0 * HDIM);
            const float4* srcv = (const float4*)(vbase + (size_t)kv0 * HDIM);
            float4* dstk = (float4*)Ks;
            float4* dstv = (float4*)Vs;
#pragma unroll
            for (int it = 0; it < 8; ++it) {
                dstk[it * 64 + t] = srck[it * 64 + t];
                dstv[it * 64 + t] = srcv[it * 64 + t];
            }
        }
        __syncthreads();

        for (int j = 0; j < 32; j += 2) {
            const float* k0 = Ks + j * 64;
            float s0 = 0.f, s1 = 0.f;
#pragma unroll
            for (int d = 0; d < 64; d += 4) {
                float4 a0 = *(const float4*)(k0 + d);
                float4 a1 = *(const float4*)(k0 + 64 + d);
                s0 += qr[d] * a0.x + qr[d + 1] * a0.y + qr[d + 2] * a0.z + qr[d + 3] * a0.w;
                s1 += qr[d] * a1.x + qr[d + 1] * a1.y + qr[d + 2] * a1.z + qr[d + 3] * a1.w;
            }
            float p0 = __expf(s0 - m) * linv;
            float p1 = __expf(s1 - m) * linv;
            const float* v0 = Vs + j * 64;
#pragma unroll
            for (int d = 0; d < 64; d += 4) {
                float4 b0 = *(const float4*)(v0 + d);
                float4 b1 = *(const float4*)(v0 + 64 + d);
                ctx[d]     += p0 * b0.x;  ctx[d]     += p1 * b1.x;
                ctx[d + 1] += p0 * b0.y;  ctx[d + 1] += p1 * b1.y;
                ctx[d + 2] += p0 * b0.z;  ctx[d + 2] += p1 * b1.z;
                ctx[d + 3] += p0 * b0.w;  ctx[d + 3] += p1 * b1.w;
            }
        }
    }

    float* dst = pctx + ((size_t)c * 32768 + row) * HDIM;
#pragma unroll
    for (int d = 0; d < 64; d += 4)
        *(float4*)(dst + d) = make_float4(ctx[d], ctx[d + 1], ctx[d + 2], ctx[d + 3]);
}

// ---------------------------------------------------------------------------
// combine partial ctx -> ctx in [B][Lq][D] layout (row l, col h*64+d)
// ---------------------------------------------------------------------------
__global__ __launch_bounds__(256)
void combine_ctx(const float* __restrict__ pctx, float* __restrict__ ctx, int C)
{
    size_t i = (size_t)blockIdx.x * 256 + threadIdx.x;   // over 32768*64
    float s = 0.f;
    for (int c = 0; c < C; ++c) s += pctx[(size_t)c * 2097152 + i];
    int d = i & 63;
    size_t r = i >> 6;
    int l = r & 1023;
    int h = (int)((r >> 10) & 15);
    int b = (int)(r >> 14);
    ctx[((size_t)b * 1024 + l) * D_MODEL + h * HDIM + d] = s;
}

// ---------------------------------------------------------------------------
// attn-mean: block per (b, 64 q rows, 64 kv cols); loops all 16 heads,
// accumulates sum_h p/16 in registers, single non-atomic write.
// LDS tiles transposed [d][row] -> conflict-free ds_read_b128 in inner loop.
// ---------------------------------------------------------------------------
__global__ __launch_bounds__(256)
void attn_mean(const float* __restrict__ q, const float* __restrict__ k,
               const float* __restrict__ mIn, const float* __restrict__ linvIn,
               float* __restrict__ attnOut)
{
    __shared__ float QsT[64][64];   // [d][qi]
    __shared__ float KsT[64][64];   // [d][kj]
    __shared__ float ms[64], ls[64];
    const int t = threadIdx.x;
    const int kt = blockIdx.x;      // 0..31
    const int qt = blockIdx.y;      // 0..15
    const int b  = blockIdx.z;      // 0..1
    const int q0 = qt * 64, kv0 = kt * 64;
    const int tx = t & 15, ty = t >> 4;
    const int li = t & 63, half = t >> 6;   // load mapping

    float att[4][4];
#pragma unroll
    for (int i = 0; i < 4; ++i)
#pragma unroll
        for (int j = 0; j < 4; ++j) att[i][j] = 0.f;

    for (int h = 0; h < HEADS; ++h) {
        __syncthreads();
        // load + transpose Q and K tiles for this head
        const float* qsrc = q + ((((size_t)b * HEADS + h) * 1024) + q0 + li) * HDIM + half * 16;
        const float* ksrc = k + ((((size_t)b * HEADS + h) * 2048) + kv0 + li) * HDIM + half * 16;
#pragma unroll
        for (int i = 0; i < 4; ++i) {
            float4 qv = *(const float4*)(qsrc + 4 * i);
            float4 kv4 = *(const float4*)(ksrc + 4 * i);
            int d = half * 16 + 4 * i;
            QsT[d + 0][li] = qv.x; QsT[d + 1][li] = qv.y;
            QsT[d + 2][li] = qv.z; QsT[d + 3][li] = qv.w;
            KsT[d + 0][li] = kv4.x; KsT[d + 1][li] = kv4.y;
            KsT[d + 2][li] = kv4.z; KsT[d + 3][li] = kv4.w;
        }
        size_t rowbase = (((size_t)b * HEADS + h) * 1024) + q0;
        if (t < 64) ms[t] = mIn[rowbase + t];
        else if (t < 128) ls[t - 64] = linvIn[rowbase + t - 64];
        __syncthreads();

        float acc[4][4];
#pragma unroll
        for (int i = 0; i < 4; ++i)
#pragma unroll
            for (int j = 0; j < 4; ++j) acc[i][j] = 0.f;

#pragma unroll 8
        for (int d = 0; d < 64; ++d) {
            float4 av = *(const float4*)&QsT[d][ty * 4];
            float4 bv = *(const float4*)&KsT[d][tx * 4];
            acc[0][0] += av.x * bv.x; acc[0][1] += av.x * bv.y;
            acc[0][2] += av.x * bv.z; acc[0][3] += av.x * bv.w;
            acc[1][0] += av.y * bv.x; acc[1][1] += av.y * bv.y;
            acc[1][2] += av.y * bv.z; acc[1][3] += av.y * bv.w;
            acc[2][0] += av.z * bv.x; acc[2][1] += av.z * bv.y;
            acc[2][2] += av.z * bv.z; acc[2][3] += av.z * bv.w;
            acc[3][0] += av.w * bv.x; acc[3][1] += av.w * bv.y;
            acc[3][2] += av.w * bv.z; acc[3][3] += av.w * bv.w;
        }

#pragma unroll
        for (int i = 0; i < 4; ++i) {
            float mrow = ms[ty * 4 + i];
            float lrow = ls[ty * 4 + i];
#pragma unroll
            for (int j = 0; j < 4; ++j)
                att[i][j] += __expf(acc[i][j] * 0.125f - mrow) * lrow;
        }
    }

    float* orow = attnOut + ((size_t)b * 1024 + q0) * 2048 + kv0;
#pragma unroll
    for (int i = 0; i < 4; ++i) {
        *(float4*)&orow[(size_t)(ty * 4 + i) * 2048 + tx * 4] =
            make_float4(att[i][0] * 0.0625f, att[i][1] * 0.0625f,
                        att[i][2] * 0.0625f, att[i][3] * 0.0625f);
    }
}

// ---------------------------------------------------------------------------
// launch
// ---------------------------------------------------------------------------
extern "C" void kernel_launch(void* const* d_in, const int* in_sizes, int n_in,
                              void* d_out, int out_size, void* d_ws, size_t ws_size,
                              hipStream_t stream)
{
    const float* x_cond  = (const float*)d_in[0];  // [2,2048,1024]
    const float* x_query = (const float*)d_in[1];  // [2,1024,1024]
    const float* tok     = (const float*)d_in[2];  // [2,1024]
    const float* w_in    = (const float*)d_in[3];  // [3072,1024]
    const float* b_in    = (const float*)d_in[4];  // [3072]
    const float* w_out   = (const float*)d_in[5];  // [1024,1024]
    const float* b_out   = (const float*)d_in[6];  // [1024]

    float* out   = (float*)d_out;
    float* fused = out;                    // 2*1024*1024
    float* attn  = out + 2097152;          // 2*1024*2048

    // choose kv-chunk count C by available workspace
    const size_t baseF = 2097152ull + 4194304ull + 4194304ull + 2097152ull + 32768ull + 32768ull;
    int C = 8;
    while (C > 1) {
        size_t needF = baseF + (size_t)C * 32768ull * 66ull;  // pm+pl+pctx
        if (needF * 4 <= ws_size) break;
        C >>= 1;
    }
    const int kvc = 2048 / C;

    float* ws   = (float*)d_ws;
    float* q    = ws;                        // 2,097,152
    float* k    = q + 2097152;               // 4,194,304
    float* v    = k + 4194304;               // 4,194,304
    float* ctx  = v + 4194304;               // 2,097,152
    float* mb   = ctx + 2097152;             // 32,768
    float* lb   = mb + 32768;                // 32,768
    float* pmb  = lb + 32768;                // C*32768
    float* plb  = pmb + (size_t)C * 32768;   // C*32768
    float* pctx = plb + (size_t)C * 32768;   // C*32768*64

    // 1. projections (tok row 0 -> cond/K/V, row 1 -> query/Q)
    gemm_proj<<<dim3(8, 16), 256, 0, stream>>>(x_query, tok + D_MODEL, w_in, b_in, q, 10, 1);
    gemm_proj<<<dim3(8, 32), 256, 0, stream>>>(x_cond, tok, w_in + 1024 * 1024, b_in + 1024, k, 11, 1);
    gemm_proj<<<dim3(8, 32), 256, 0, stream>>>(x_cond, tok, w_in + 2 * 1024 * 1024, b_in + 2048, v, 11, 1);

    // 2. attention: chunked m/l -> combine -> chunked pv -> combine
    attn_ml<<<dim3(16 * C, 16, 2), 64, 0, stream>>>(q, k, pmb, plb, kvc);
    combine_ml<<<128, 256, 0, stream>>>(pmb, plb, mb, lb, C);
    attn_pv<<<dim3(16 * C, 16, 2), 64, 0, stream>>>(q, k, v, mb, lb, pctx, kvc);
    attn_mean<<<dim3(32, 16, 2), 256, 0, stream>>>(q, k, mb, lb, attn);
    combine_ctx<<<8192, 256, 0, stream>>>(pctx, ctx, C);

    // 3. output projection
    gemm_proj<<<dim3(8, 16), 256, 0, stream>>>(ctx, nullptr, w_out, b_out, fused, 0, 0);
}

// Round 4
// 314.250 us; speedup vs baseline: 12.6129x; 4.6329x over previous
//
#include <hip/hip_runtime.h>
#include <hip/hip_bf16.h>
#include <cstddef>
#include <cstdint>

// B=2, Lq=1024, Lkv=2048, D=1024, H=16, hd=64.  All MFMA = 16x16x32 bf16.

typedef float  f32x4  __attribute__((ext_vector_type(4)));
typedef short  bf16x8 __attribute__((ext_vector_type(8)));
typedef unsigned short u16x8 __attribute__((ext_vector_type(8)));
typedef __attribute__((address_space(1))) const void gvoid;
typedef __attribute__((address_space(3))) void lvoid;
#define GLD16(g, l) __builtin_amdgcn_global_load_lds((gvoid*)(g), (lvoid*)(l), 16, 0, 0)
#define LOG2E 1.4426950408889634f

static __device__ __forceinline__ unsigned short f2bf(float f) {
    union { float f; unsigned u; } v; v.f = f;
    unsigned r = v.u + 0x7fff + ((v.u >> 16) & 1);   // RNE
    return (unsigned short)(r >> 16);
}

// ---------------------------------------------------------------------------
// f32 (+ optional per-column tok add, cols mod 1024) -> bf16, 8 elems/thread
// ---------------------------------------------------------------------------
__global__ __launch_bounds__(256)
void conv_bf16(const float* __restrict__ x, const float* __restrict__ tok,
               unsigned short* __restrict__ out, int n8)
{
    int i = blockIdx.x * 256 + threadIdx.x;
    if (i >= n8) return;
    const float4* src = (const float4*)x + (size_t)i * 2;
    float4 a = src[0], b = src[1];
    if (tok) {
        int col = (i * 8) & 1023;
        const float4* tp = (const float4*)(tok + col);
        float4 t0 = tp[0], t1 = tp[1];
        a.x += t0.x; a.y += t0.y; a.z += t0.z; a.w += t0.w;
        b.x += t1.x; b.y += t1.y; b.z += t1.z; b.w += t1.w;
    }
    u16x8 r;
    r[0] = f2bf(a.x); r[1] = f2bf(a.y); r[2] = f2bf(a.z); r[3] = f2bf(a.w);
    r[4] = f2bf(b.x); r[5] = f2bf(b.y); r[6] = f2bf(b.z); r[7] = f2bf(b.w);
    ((u16x8*)out)[i] = r;
}

// ---------------------------------------------------------------------------
// MFMA GEMM: C[m][n] = sum_k A[m][k]*W[n][k] + bias[n], A/W bf16 K-major.
// 128x128 tile, BK=64, 4 waves (2x2), 4x4 16x16 frags per wave.
// XOR-swizzled LDS (chunk ^= row&7) with pre-swizzled global_load_lds source.
// mode 0: f32 flat [M][1024].  mode 1: bf16 head layout [b][h][L][64], *scale.
// ---------------------------------------------------------------------------
__global__ __launch_bounds__(256)
void gemm_mfma(const unsigned short* __restrict__ A,
               const unsigned short* __restrict__ W,
               const float* __restrict__ bias,
               void* __restrict__ Y, int Lshift, float scale, int mode)
{
    __shared__ unsigned short As[128 * 64];
    __shared__ unsigned short Bs[128 * 64];
    const int t  = threadIdx.x;
    const int wv = t >> 6, ln = t & 63;
    const int wr = wv >> 1, wc = wv & 1;
    const int lr = ln & 15, lg = ln >> 4;
    const int m0 = blockIdx.y * 128, n0 = blockIdx.x * 128;

    f32x4 acc[4][4] = {};

    for (int k0 = 0; k0 < 1024; k0 += 64) {
        __syncthreads();
#pragma unroll
        for (int ia = 0; ia < 4; ++ia) {
            int idx = ia * 256 + t;
            int row = idx >> 3, c = idx & 7;
            int sw = (c ^ (row & 7)) * 8;
            GLD16(A + (size_t)(m0 + row) * 1024 + k0 + sw, As + idx * 8);
            GLD16(W + (size_t)(n0 + row) * 1024 + k0 + sw, Bs + idx * 8);
        }
        asm volatile("s_waitcnt vmcnt(0)" ::: "memory");
        __syncthreads();
#pragma unroll
        for (int ks = 0; ks < 2; ++ks) {
            bf16x8 af[4], bf[4];
#pragma unroll
            for (int i = 0; i < 4; ++i) {
                int rowA = wr * 64 + i * 16 + lr;
                af[i] = *(const bf16x8*)(As + rowA * 64 + (((ks * 4 + lg) ^ (rowA & 7)) * 8));
                int rowB = wc * 64 + i * 16 + lr;
                bf[i] = *(const bf16x8*)(Bs + rowB * 64 + (((ks * 4 + lg) ^ (rowB & 7)) * 8));
            }
#pragma unroll
            for (int i = 0; i < 4; ++i)
#pragma unroll
                for (int j = 0; j < 4; ++j)
                    acc[i][j] = __builtin_amdgcn_mfma_f32_16x16x32_bf16(af[i], bf[j], acc[i][j], 0, 0, 0);
        }
    }

#pragma unroll
    for (int i = 0; i < 4; ++i) {
        int rb = m0 + wr * 64 + i * 16 + lg * 4;
#pragma unroll
        for (int j = 0; j < 4; ++j) {
            int col = n0 + wc * 64 + j * 16 + lr;
            float bv = bias[col];
#pragma unroll
            for (int rr = 0; rr < 4; ++rr) {
                float v = (acc[i][j][rr] + bv) * scale;
                int r = rb + rr;
                if (mode == 0) {
                    ((float*)Y)[(size_t)r * 1024 + col] = v;
                } else {
                    int b = r >> Lshift, l = r & ((1 << Lshift) - 1);
                    int h = col >> 6, d = col & 63;
                    ((unsigned short*)Y)[((((size_t)b * 16 + h) << Lshift) + l) * 64 + d] = f2bf(v);
                }
            }
        }
    }
}

// ---------------------------------------------------------------------------
// Vh[b][h][2048][64] -> Vt[b][h][64][2048]  (bf16 transpose via LDS)
// ---------------------------------------------------------------------------
__global__ __launch_bounds__(256)
void transpose_v(const unsigned short* __restrict__ Vh, unsigned short* __restrict__ Vt)
{
    __shared__ unsigned short L[64 * 72];
    const int t = threadIdx.x;
    const int kt = blockIdx.x;   // 0..31 kv tile
    const int bh = blockIdx.y;   // 0..31
    const unsigned short* src = Vh + ((size_t)bh * 2048 + kt * 64) * 64;
#pragma unroll
    for (int i = 0; i < 2; ++i) {
        int idx = i * 256 + t;
        int kv = idx >> 3, c = idx & 7;
        *(bf16x8*)(L + kv * 72 + c * 8) = *(const bf16x8*)(src + kv * 64 + c * 8);
    }
    __syncthreads();
#pragma unroll
    for (int i = 0; i < 2; ++i) {
        int idx = i * 256 + t;
        int d = idx >> 3, ck = idx & 7;
        u16x8 r;
#pragma unroll
        for (int j = 0; j < 8; ++j) r[j] = L[(ck * 8 + j) * 72 + d];
        *(u16x8*)(Vt + ((size_t)bh * 64 + d) * 2048 + kt * 64 + ck * 8) = r;
    }
}

// ---------------------------------------------------------------------------
// Single-pass flash attention (online softmax, exp2 domain).
// Block: 4 waves x 16 q rows, KV tile 64. Q pre-scaled by 0.125.
// Writes ctx bf16 [2048][1024] (flat, col = h*64+d), m2 (log2 max), linv.
// ---------------------------------------------------------------------------
__global__ __launch_bounds__(256)
void flash_fwd(const unsigned short* __restrict__ Q,
               const unsigned short* __restrict__ K,
               const unsigned short* __restrict__ Vt,
               unsigned short* __restrict__ ctx,
               float* __restrict__ m2Out, float* __restrict__ linvOut)
{
    __shared__ unsigned short Ks[64 * 64];
    __shared__ unsigned short Vs[64 * 64];
    __shared__ unsigned short Ps[64 * 72];
    const int t  = threadIdx.x;
    const int wv = t >> 6, ln = t & 63;
    const int lr = ln & 15, lg = ln >> 4;
    const int qt = blockIdx.x, h = blockIdx.y, b = blockIdx.z;
    const int bh = b * 16 + h;
    const int q0 = qt * 64;

    bf16x8 qf[2];
    {
        const unsigned short* qp = Q + ((size_t)bh * 1024 + q0 + wv * 16 + lr) * 64 + lg * 8;
        qf[0] = *(const bf16x8*)qp;
        qf[1] = *(const bf16x8*)(qp + 32);
    }

    f32x4 cacc[4] = {};
    float m2[4], lsum[4];
#pragma unroll
    for (int rr = 0; rr < 4; ++rr) { m2[rr] = -1e30f; lsum[rr] = 0.f; }

    const unsigned short* kb = K  + (size_t)bh * 2048 * 64;
    const unsigned short* vb = Vt + (size_t)bh * 64 * 2048;

    for (int kv0 = 0; kv0 < 2048; kv0 += 64) {
        __syncthreads();
#pragma unroll
        for (int i = 0; i < 2; ++i) {
            int idx = i * 256 + t;
            int row = idx >> 3, c = idx & 7;
            int sw = (c ^ (row & 7)) * 8;
            GLD16(kb + (size_t)(kv0 + row) * 64 + sw, Ks + idx * 8);
            GLD16(vb + (size_t)row * 2048 + kv0 + sw, Vs + idx * 8);
        }
        asm volatile("s_waitcnt vmcnt(0)" ::: "memory");
        __syncthreads();

        // S = Q K^T
        f32x4 sacc[4] = {};
#pragma unroll
        for (int ks = 0; ks < 2; ++ks) {
#pragma unroll
            for (int cf = 0; cf < 4; ++cf) {
                int rowK = cf * 16 + lr;
                bf16x8 kf = *(const bf16x8*)(Ks + rowK * 64 + (((ks * 4 + lg) ^ (rowK & 7)) * 8));
                sacc[cf] = __builtin_amdgcn_mfma_f32_16x16x32_bf16(qf[ks], kf, sacc[cf], 0, 0, 0);
            }
        }

        // online softmax: row r of D-frag = lg*4+rr, cols across the 16 lanes
        float sc[4];
#pragma unroll
        for (int rr = 0; rr < 4; ++rr) {
            float rm = fmaxf(fmaxf(sacc[0][rr], sacc[1][rr]), fmaxf(sacc[2][rr], sacc[3][rr]));
#pragma unroll
            for (int off = 1; off < 16; off <<= 1)
                rm = fmaxf(rm, __shfl_xor(rm, off, 64));
            rm *= LOG2E;
            float nm = fmaxf(m2[rr], rm);
            sc[rr] = exp2f(m2[rr] - nm);
            m2[rr] = nm;
        }
        float rsum[4] = {0.f, 0.f, 0.f, 0.f};
#pragma unroll
        for (int cf = 0; cf < 4; ++cf) {
#pragma unroll
            for (int rr = 0; rr < 4; ++rr) {
                float p = exp2f(sacc[cf][rr] * LOG2E - m2[rr]);
                rsum[rr] += p;
                Ps[(wv * 16 + lg * 4 + rr) * 72 + cf * 16 + lr] = f2bf(p);
            }
        }
#pragma unroll
        for (int rr = 0; rr < 4; ++rr) {
            float s = rsum[rr];
#pragma unroll
            for (int off = 1; off < 16; off <<= 1)
                s += __shfl_xor(s, off, 64);
            lsum[rr] = lsum[rr] * sc[rr] + s;
#pragma unroll
            for (int df = 0; df < 4; ++df) cacc[df][rr] *= sc[rr];
        }
        __syncthreads();   // P visible (also orders before next staging)

        // ctx += P V
#pragma unroll
        for (int kvs = 0; kvs < 2; ++kvs) {
            bf16x8 pf = *(const bf16x8*)(Ps + (wv * 16 + lr) * 72 + kvs * 32 + lg * 8);
#pragma unroll
            for (int df = 0; df < 4; ++df) {
                int rowV = df * 16 + lr;
                bf16x8 vf = *(const bf16x8*)(Vs + rowV * 64 + (((kvs * 4 + lg) ^ (rowV & 7)) * 8));
                cacc[df] = __builtin_amdgcn_mfma_f32_16x16x32_bf16(pf, vf, cacc[df], 0, 0, 0);
            }
        }
    }

    float inv[4];
#pragma unroll
    for (int rr = 0; rr < 4; ++rr) inv[rr] = 1.f / lsum[rr];
#pragma unroll
    for (int df = 0; df < 4; ++df) {
#pragma unroll
        for (int rr = 0; rr < 4; ++rr) {
            int row = q0 + wv * 16 + lg * 4 + rr;
            int col = h * 64 + df * 16 + lr;
            ctx[((size_t)b * 1024 + row) * 1024 + col] = f2bf(cacc[df][rr] * inv[rr]);
        }
    }
    if (lr == 0) {
#pragma unroll
        for (int rr = 0; rr < 4; ++rr) {
            size_t idx = (size_t)bh * 1024 + q0 + wv * 16 + lg * 4 + rr;
            m2Out[idx]   = m2[rr];
            linvOut[idx] = inv[rr];
        }
    }
}

// ---------------------------------------------------------------------------
// attn-mean: block per (b, 64q, 64kv), loops 16 heads; S by MFMA (identical
// to flash), p = exp2(S*log2e - m2)*linv, accumulate, one write. No atomics.
// ---------------------------------------------------------------------------
__global__ __launch_bounds__(256)
void attn_mean_mfma(const unsigned short* __restrict__ Q,
                    const unsigned short* __restrict__ K,
                    const float* __restrict__ m2In, const float* __restrict__ linvIn,
                    float* __restrict__ attnOut)
{
    __shared__ unsigned short Ks[64 * 64];
    const int t  = threadIdx.x;
    const int wv = t >> 6, ln = t & 63;
    const int lr = ln & 15, lg = ln >> 4;
    const int kt = blockIdx.x, qt = blockIdx.y, b = blockIdx.z;
    const int q0 = qt * 64, kv0 = kt * 64;

    float att[4][4] = {};

    for (int h = 0; h < 16; ++h) {
        const int bh = b * 16 + h;
        __syncthreads();
#pragma unroll
        for (int i = 0; i < 2; ++i) {
            int idx = i * 256 + t;
            int row = idx >> 3, c = idx & 7;
            GLD16(K + ((size_t)bh * 2048 + kv0 + row) * 64 + ((c ^ (row & 7)) * 8), Ks + idx * 8);
        }
        const unsigned short* qp = Q + ((size_t)bh * 1024 + q0 + wv * 16 + lr) * 64 + lg * 8;
        bf16x8 qf0 = *(const bf16x8*)qp;
        bf16x8 qf1 = *(const bf16x8*)(qp + 32);
        float m2r[4], lir[4];
#pragma unroll
        for (int rr = 0; rr < 4; ++rr) {
            size_t ridx = (size_t)bh * 1024 + q0 + wv * 16 + lg * 4 + rr;
            m2r[rr] = m2In[ridx]; lir[rr] = linvIn[ridx];
        }
        asm volatile("s_waitcnt vmcnt(0)" ::: "memory");
        __syncthreads();

        f32x4 sacc[4] = {};
#pragma unroll
        for (int cf = 0; cf < 4; ++cf) {
            int rowK = cf * 16 + lr;
            bf16x8 kf0 = *(const bf16x8*)(Ks + rowK * 64 + ((lg ^ (rowK & 7)) * 8));
            sacc[cf] = __builtin_amdgcn_mfma_f32_16x16x32_bf16(qf0, kf0, sacc[cf], 0, 0, 0);
            bf16x8 kf1 = *(const bf16x8*)(Ks + rowK * 64 + (((4 + lg) ^ (rowK & 7)) * 8));
            sacc[cf] = __builtin_amdgcn_mfma_f32_16x16x32_bf16(qf1, kf1, sacc[cf], 0, 0, 0);
        }
#pragma unroll
        for (int cf = 0; cf < 4; ++cf)
#pragma unroll
            for (int rr = 0; rr < 4; ++rr)
                att[cf][rr] += exp2f(sacc[cf][rr] * LOG2E - m2r[rr]) * lir[rr];
    }

#pragma unroll
    for (int cf = 0; cf < 4; ++cf)
#pragma unroll
        for (int rr = 0; rr < 4; ++rr) {
            int row = q0 + wv * 16 + lg * 4 + rr;
            int col = kv0 + cf * 16 + lr;
            attnOut[((size_t)b * 1024 + row) * 2048 + col] = att[cf][rr] * 0.0625f;
        }
}

// ---------------------------------------------------------------------------
// launch
// ---------------------------------------------------------------------------
extern "C" void kernel_launch(void* const* d_in, const int* in_sizes, int n_in,
                              void* d_out, int out_size, void* d_ws, size_t ws_size,
                              hipStream_t stream)
{
    const float* x_cond  = (const float*)d_in[0];
    const float* x_query = (const float*)d_in[1];
    const float* tok     = (const float*)d_in[2];
    const float* w_in    = (const float*)d_in[3];
    const float* b_in    = (const float*)d_in[4];
    const float* w_out   = (const float*)d_in[5];
    const float* b_out   = (const float*)d_in[6];

    float* fused = (float*)d_out;
    float* attn  = (float*)d_out + 2097152;

    unsigned short* ws = (unsigned short*)d_ws;
    unsigned short* Aq   = ws;              // 2M halves
    unsigned short* Ac   = Aq   + 2097152;  // 4M
    unsigned short* Wb   = Ac   + 4194304;  // 4M (wq,wk,wv,wo rows)
    unsigned short* Qh   = Wb   + 4194304;  // 2M
    unsigned short* Kh   = Qh   + 2097152;  // 4M
    unsigned short* Vh   = Kh   + 4194304;  // 4M
    unsigned short* Vt   = Vh   + 4194304;  // 4M
    unsigned short* ctxb = Vt   + 4194304;  // 2M
    float* m2b = (float*)(ctxb + 2097152);  // 32768
    float* lib = m2b + 32768;               // 32768

    // 1. bf16 conversions (tok[1] -> query, tok[0] -> cond)
    conv_bf16<<<1024, 256, 0, stream>>>(x_query, tok + 1024, Aq, 262144);
    conv_bf16<<<2048, 256, 0, stream>>>(x_cond,  tok,        Ac, 524288);
    conv_bf16<<<1536, 256, 0, stream>>>(w_in,  nullptr, Wb,           393216);
    conv_bf16<<< 512, 256, 0, stream>>>(w_out, nullptr, Wb + 3145728, 131072);

    // 2. projections (Q scaled by 0.125 = softmax scale, folded)
    gemm_mfma<<<dim3(8, 16), 256, 0, stream>>>(Aq, Wb,           b_in,        Qh, 10, 0.125f, 1);
    gemm_mfma<<<dim3(8, 32), 256, 0, stream>>>(Ac, Wb + 1048576, b_in + 1024, Kh, 11, 1.0f,   1);
    gemm_mfma<<<dim3(8, 32), 256, 0, stream>>>(Ac, Wb + 2097152, b_in + 2048, Vh, 11, 1.0f,   1);

    // 3. V transpose -> [bh][64][2048]
    transpose_v<<<dim3(32, 32), 256, 0, stream>>>(Vh, Vt);

    // 4. attention
    flash_fwd<<<dim3(16, 16, 2), 256, 0, stream>>>(Qh, Kh, Vt, ctxb, m2b, lib);
    attn_mean_mfma<<<dim3(32, 16, 2), 256, 0, stream>>>(Qh, Kh, m2b, lib, attn);

    // 5. output projection (f32 out)
    gemm_mfma<<<dim3(8, 16), 256, 0, stream>>>(ctxb, Wb + 3145728, b_out, fused, 0, 1.0f, 0);
}

// Round 6
// 304.896 us; speedup vs baseline: 12.9998x; 1.0307x over previous
//
#include <hip/hip_runtime.h>
#include <hip/hip_bf16.h>
#include <cstddef>
#include <cstdint>

// B=2, Lq=1024, Lkv=2048, D=1024, H=16, hd=64.  All MFMA = 16x16x32 bf16.

typedef float  f32x4  __attribute__((ext_vector_type(4)));
typedef short  bf16x8 __attribute__((ext_vector_type(8)));
typedef unsigned short u16x8 __attribute__((ext_vector_type(8)));
typedef __attribute__((address_space(1))) const void gvoid;
typedef __attribute__((address_space(3))) void lvoid;
#define GLD16(g, l) __builtin_amdgcn_global_load_lds((gvoid*)(g), (lvoid*)(l), 16, 0, 0)
#define WAIT_VM0()   asm volatile("s_waitcnt vmcnt(0)" ::: "memory")
#define WAIT_LGKM0() asm volatile("s_waitcnt lgkmcnt(0)" ::: "memory")
#define BAR() __builtin_amdgcn_s_barrier()
#define LOG2E 1.4426950408889634f

static __device__ __forceinline__ unsigned short f2bf(float f) {
    union { float f; unsigned u; } v; v.f = f;
    unsigned r = v.u + 0x7fff + ((v.u >> 16) & 1);   // RNE
    return (unsigned short)(r >> 16);
}

// ---------------------------------------------------------------------------
// f32 (+ optional per-column tok add, cols mod 1024) -> bf16, 8 elems/thread
// ---------------------------------------------------------------------------
__global__ __launch_bounds__(256)
void conv_bf16(const float* __restrict__ x, const float* __restrict__ tok,
               unsigned short* __restrict__ out, int n8)
{
    int i = blockIdx.x * 256 + threadIdx.x;
    if (i >= n8) return;
    const float4* src = (const float4*)x + (size_t)i * 2;
    float4 a = src[0], b = src[1];
    if (tok) {
        int col = (i * 8) & 1023;
        const float4* tp = (const float4*)(tok + col);
        float4 t0 = tp[0], t1 = tp[1];
        a.x += t0.x; a.y += t0.y; a.z += t0.z; a.w += t0.w;
        b.x += t1.x; b.y += t1.y; b.z += t1.z; b.w += t1.w;
    }
    u16x8 r;
    r[0] = f2bf(a.x); r[1] = f2bf(a.y); r[2] = f2bf(a.z); r[3] = f2bf(a.w);
    r[4] = f2bf(b.x); r[5] = f2bf(b.y); r[6] = f2bf(b.z); r[7] = f2bf(b.w);
    ((u16x8*)out)[i] = r;
}

// ---------------------------------------------------------------------------
// MFMA GEMM: C[m][n] = sum_k A[m][k]*W[n][k] + bias[n], A/W bf16 K-major.
// 128x128 tile, BK=64, 4 waves (2x2), 4x4 16x16 frags per wave.
// XOR-swizzled LDS with pre-swizzled global_load_lds source.  (unchanged)
// ---------------------------------------------------------------------------
__global__ __launch_bounds__(256)
void gemm_mfma(const unsigned short* __restrict__ A,
               const unsigned short* __restrict__ W,
               const float* __restrict__ bias,
               void* __restrict__ Y, int Lshift, float scale, int mode)
{
    __shared__ unsigned short As[128 * 64];
    __shared__ unsigned short Bs[128 * 64];
    const int t  = threadIdx.x;
    const int wv = t >> 6, ln = t & 63;
    const int wr = wv >> 1, wc = wv & 1;
    const int lr = ln & 15, lg = ln >> 4;
    const int m0 = blockIdx.y * 128, n0 = blockIdx.x * 128;

    f32x4 acc[4][4] = {};

    for (int k0 = 0; k0 < 1024; k0 += 64) {
        __syncthreads();
#pragma unroll
        for (int ia = 0; ia < 4; ++ia) {
            int idx = ia * 256 + t;
            int row = idx >> 3, c = idx & 7;
            int sw = (c ^ (row & 7)) * 8;
            GLD16(A + (size_t)(m0 + row) * 1024 + k0 + sw, As + idx * 8);
            GLD16(W + (size_t)(n0 + row) * 1024 + k0 + sw, Bs + idx * 8);
        }
        WAIT_VM0();
        __syncthreads();
#pragma unroll
        for (int ks = 0; ks < 2; ++ks) {
            bf16x8 af[4], bf[4];
#pragma unroll
            for (int i = 0; i < 4; ++i) {
                int rowA = wr * 64 + i * 16 + lr;
                af[i] = *(const bf16x8*)(As + rowA * 64 + (((ks * 4 + lg) ^ (rowA & 7)) * 8));
                int rowB = wc * 64 + i * 16 + lr;
                bf[i] = *(const bf16x8*)(Bs + rowB * 64 + (((ks * 4 + lg) ^ (rowB & 7)) * 8));
            }
#pragma unroll
            for (int i = 0; i < 4; ++i)
#pragma unroll
                for (int j = 0; j < 4; ++j)
                    acc[i][j] = __builtin_amdgcn_mfma_f32_16x16x32_bf16(af[i], bf[j], acc[i][j], 0, 0, 0);
        }
    }

#pragma unroll
    for (int i = 0; i < 4; ++i) {
        int rb = m0 + wr * 64 + i * 16 + lg * 4;
#pragma unroll
        for (int j = 0; j < 4; ++j) {
            int col = n0 + wc * 64 + j * 16 + lr;
            float bv = bias[col];
#pragma unroll
            for (int rr = 0; rr < 4; ++rr) {
                float v = (acc[i][j][rr] + bv) * scale;
                int r = rb + rr;
                if (mode == 0) {
                    ((float*)Y)[(size_t)r * 1024 + col] = v;
                } else {
                    int b = r >> Lshift, l = r & ((1 << Lshift) - 1);
                    int h = col >> 6, d = col & 63;
                    ((unsigned short*)Y)[((((size_t)b * 16 + h) << Lshift) + l) * 64 + d] = f2bf(v);
                }
            }
        }
    }
}

// ---------------------------------------------------------------------------
// Vh[b][h][2048][64] -> Vt[b][h][64][2048]  (bf16 transpose via LDS)
// ---------------------------------------------------------------------------
__global__ __launch_bounds__(256)
void transpose_v(const unsigned short* __restrict__ Vh, unsigned short* __restrict__ Vt)
{
    __shared__ unsigned short L[64 * 72];
    const int t = threadIdx.x;
    const int kt = blockIdx.x;   // 0..31 kv tile
    const int bh = blockIdx.y;   // 0..31
    const unsigned short* src = Vh + ((size_t)bh * 2048 + kt * 64) * 64;
#pragma unroll
    for (int i = 0; i < 2; ++i) {
        int idx = i * 256 + t;
        int kv = idx >> 3, c = idx & 7;
        *(bf16x8*)(L + kv * 72 + c * 8) = *(const bf16x8*)(src + kv * 64 + c * 8);
    }
    __syncthreads();
#pragma unroll
    for (int i = 0; i < 2; ++i) {
        int idx = i * 256 + t;
        int d = idx >> 3, ck = idx & 7;
        u16x8 r;
#pragma unroll
        for (int j = 0; j < 8; ++j) r[j] = L[(ck * 8 + j) * 72 + d];
        *(u16x8*)(Vt + ((size_t)bh * 64 + d) * 2048 + kt * 64 + ck * 8) = r;
    }
}

// ---------------------------------------------------------------------------
// Single-pass flash attention, 2-phase double-buffered K/V staging.
// Block: 4 waves x 16 q rows, KV tile 64. Q pre-scaled by 0.125.
// Raw s_barrier + counted waits: next tile's global_load_lds stays in
// flight under QK/softmax/PV.  Frag LDS offsets hoisted (ks=1 == ks=0 ^ 32).
// ---------------------------------------------------------------------------
__global__ __launch_bounds__(256)
void flash_fwd(const unsigned short* __restrict__ Q,
               const unsigned short* __restrict__ K,
               const unsigned short* __restrict__ Vt,
               unsigned short* __restrict__ ctx,
               float* __restrict__ m2Out, float* __restrict__ linvOut)
{
    __shared__ unsigned short Ks[2][64 * 64];
    __shared__ unsigned short Vs[2][64 * 64];
    __shared__ unsigned short Ps[64 * 72];
    const int t  = threadIdx.x;
    const int wv = t >> 6, ln = t & 63;
    const int lr = ln & 15, lg = ln >> 4;
    const int qt = blockIdx.x, h = blockIdx.y, b = blockIdx.z;
    const int bh = b * 16 + h;
    const int q0 = qt * 64;

    // staging map: 2 x 16B chunks per thread per matrix
    const int i0 = t, i1 = 256 + t;
    const int r0 = i0 >> 3, c0 = i0 & 7, sw0 = (c0 ^ (r0 & 7)) * 8;
    const int r1 = i1 >> 3, c1 = i1 & 7, sw1 = (c1 ^ (r1 & 7)) * 8;
    const int l0 = i0 * 8, l1 = i1 * 8;
    const int gk0 = r0 * 64 + sw0,   gk1 = r1 * 64 + sw1;
    const int gv0 = r0 * 2048 + sw0, gv1 = r1 * 2048 + sw1;

    // loop-invariant fragment offsets (K and V share the formula)
    int koff[4];
#pragma unroll
    for (int cf = 0; cf < 4; ++cf)
        koff[cf] = (cf * 16 + lr) * 64 + ((lg ^ (lr & 7)) * 8);
    const int pw  = (wv * 16 + lg * 4) * 72 + lr;
    const int pr0 = (wv * 16 + lr) * 72 + lg * 8;

    bf16x8 qf[2];
    {
        const unsigned short* qp = Q + ((size_t)bh * 1024 + q0 + wv * 16 + lr) * 64 + lg * 8;
        qf[0] = *(const bf16x8*)qp;
        qf[1] = *(const bf16x8*)(qp + 32);
    }

    f32x4 cacc[4] = {};
    float m2[4], lsum[4];
#pragma unroll
    for (int rr = 0; rr < 4; ++rr) { m2[rr] = -1e30f; lsum[rr] = 0.f; }

    const unsigned short* kp = K  + (size_t)bh * 2048 * 64;
    const unsigned short* vp = Vt + (size_t)bh * 64 * 2048;

    // prologue: stage tile 0 into buf 0
    GLD16(kp + gk0, &Ks[0][l0]); GLD16(kp + gk1, &Ks[0][l1]);
    GLD16(vp + gv0, &Vs[0][l0]); GLD16(vp + gv1, &Vs[0][l1]);
    kp += 4096; vp += 64;
    WAIT_VM0();
    BAR();

    int cur = 0;
    for (int tile = 0; tile < 32; ++tile) {
        if (tile < 31) {   // stage next tile into the other buffer (stays in flight)
            GLD16(kp + gk0, &Ks[cur ^ 1][l0]); GLD16(kp + gk1, &Ks[cur ^ 1][l1]);
            GLD16(vp + gv0, &Vs[cur ^ 1][l0]); GLD16(vp + gv1, &Vs[cur ^ 1][l1]);
            kp += 4096; vp += 64;
        }

        // S = Q K^T
        f32x4 sacc[4] = {};
#pragma unroll
        for (int cf = 0; cf < 4; ++cf) {
            bf16x8 kf0 = *(const bf16x8*)(Ks[cur] + koff[cf]);
            sacc[cf] = __builtin_amdgcn_mfma_f32_16x16x32_bf16(qf[0], kf0, sacc[cf], 0, 0, 0);
            bf16x8 kf1 = *(const bf16x8*)(Ks[cur] + (koff[cf] ^ 32));
            sacc[cf] = __builtin_amdgcn_mfma_f32_16x16x32_bf16(qf[1], kf1, sacc[cf], 0, 0, 0);
        }

        // online softmax (exp2 domain); defer-rescale when max doesn't grow
        float rm[4];
#pragma unroll
        for (int rr = 0; rr < 4; ++rr) {
            float v = fmaxf(fmaxf(sacc[0][rr], sacc[1][rr]), fmaxf(sacc[2][rr], sacc[3][rr]));
#pragma unroll
            for (int off = 1; off < 16; off <<= 1) v = fmaxf(v, __shfl_xor(v, off, 64));
            rm[rr] = v * LOG2E;
        }
        int grow = (rm[0] > m2[0]) | (rm[1] > m2[1]) | (rm[2] > m2[2]) | (rm[3] > m2[3]);
        if (__any(grow)) {   // exact skip: sc==1 when max unchanged
#pragma unroll
            for (int rr = 0; rr < 4; ++rr) {
                float nm = fmaxf(m2[rr], rm[rr]);
                float sc = exp2f(m2[rr] - nm);
                m2[rr] = nm;
                lsum[rr] *= sc;
#pragma unroll
                for (int df = 0; df < 4; ++df) cacc[df][rr] *= sc;
            }
        }
        float rsum[4] = {0.f, 0.f, 0.f, 0.f};
#pragma unroll
        for (int cf = 0; cf < 4; ++cf) {
#pragma unroll
            for (int rr = 0; rr < 4; ++rr) {
                float p = exp2f(sacc[cf][rr] * LOG2E - m2[rr]);
                rsum[rr] += p;
                Ps[pw + rr * 72 + cf * 16] = f2bf(p);
            }
        }
#pragma unroll
        for (int rr = 0; rr < 4; ++rr) {
            float s = rsum[rr];
#pragma unroll
            for (int off = 1; off < 16; off <<= 1) s += __shfl_xor(s, off, 64);
            lsum[rr] += s;
        }
        WAIT_LGKM0();
        BAR();                         // Ps visible; staged loads still in flight

        // ctx += P V
#pragma unroll
        for (int kvs = 0; kvs < 2; ++kvs) {
            bf16x8 pf = *(const bf16x8*)(Ps + pr0 + kvs * 32);
#pragma unroll
            for (int df = 0; df < 4; ++df) {
                bf16x8 vf = *(const bf16x8*)(Vs[cur] + (koff[df] ^ (kvs * 32)));
                cacc[df] = __builtin_amdgcn_mfma_f32_16x16x32_bf16(pf, vf, cacc[df], 0, 0, 0);
            }
        }
        WAIT_VM0();                    // next tile's staging complete
        BAR();                         // all waves done reading buf[cur] + Ps
        cur ^= 1;
    }

    float inv[4];
#pragma unroll
    for (int rr = 0; rr < 4; ++rr) inv[rr] = 1.f / lsum[rr];
#pragma unroll
    for (int df = 0; df < 4; ++df) {
#pragma unroll
        for (int rr = 0; rr < 4; ++rr) {
            int row = q0 + wv * 16 + lg * 4 + rr;
            int col = h * 64 + df * 16 + lr;
            ctx[((size_t)b * 1024 + row) * 1024 + col] = f2bf(cacc[df][rr] * inv[rr]);
        }
    }
    if (lr == 0) {
#pragma unroll
        for (int rr = 0; rr < 4; ++rr) {
            size_t idx = (size_t)bh * 1024 + q0 + wv * 16 + lg * 4 + rr;
            m2Out[idx]   = m2[rr];
            linvOut[idx] = inv[rr];
        }
    }
}

// ---------------------------------------------------------------------------
// attn-mean: block per (b, 64q, 64kv); loops 16 heads with double-buffered
// K staging (stage h+1 while computing h). S by MFMA identical to flash.
// ---------------------------------------------------------------------------
__global__ __launch_bounds__(256)
void attn_mean_mfma(const unsigned short* __restrict__ Q,
                    const unsigned short* __restrict__ K,
                    const float* __restrict__ m2In, const float* __restrict__ linvIn,
                    float* __restrict__ attnOut)
{
    __shared__ unsigned short Ks[2][64 * 64];
    const int t  = threadIdx.x;
    const int wv = t >> 6, ln = t & 63;
    const int lr = ln & 15, lg = ln >> 4;
    const int kt = blockIdx.x, qt = blockIdx.y, b = blockIdx.z;
    const int q0 = qt * 64, kv0 = kt * 64;

    const int i0 = t, i1 = 256 + t;
    const int r0 = i0 >> 3, c0 = i0 & 7, sw0 = (c0 ^ (r0 & 7)) * 8;
    const int r1 = i1 >> 3, c1 = i1 & 7, sw1 = (c1 ^ (r1 & 7)) * 8;
    const int l0 = i0 * 8, l1 = i1 * 8;
    const int gk0 = r0 * 64 + sw0, gk1 = r1 * 64 + sw1;

    int koff[4];
#pragma unroll
    for (int cf = 0; cf < 4; ++cf)
        koff[cf] = (cf * 16 + lr) * 64 + ((lg ^ (lr & 7)) * 8);

    const unsigned short* kp = K + ((size_t)(b * 16) * 2048 + kv0) * 64;
    const unsigned short* qp = Q + ((size_t)(b * 16) * 1024 + q0 + wv * 16 + lr) * 64 + lg * 8;
    size_t ridx = (size_t)(b * 16) * 1024 + q0 + wv * 16 + lg * 4;

    float att[4][4] = {};

    // prologue: stage head 0
    GLD16(kp + gk0, &Ks[0][l0]); GLD16(kp + gk1, &Ks[0][l1]);
    kp += 131072;
    WAIT_VM0();
    BAR();

    int cur = 0;
    for (int h = 0; h < 16; ++h) {
        if (h < 15) {
            GLD16(kp + gk0, &Ks[cur ^ 1][l0]); GLD16(kp + gk1, &Ks[cur ^ 1][l1]);
            kp += 131072;
        }
        bf16x8 qf0 = *(const bf16x8*)qp;
        bf16x8 qf1 = *(const bf16x8*)(qp + 32);
        qp += 65536;
        float m2r[4], lir[4];
#pragma unroll
        for (int rr = 0; rr < 4; ++rr) {
            m2r[rr] = m2In[ridx + rr];
            lir[rr] = linvIn[ridx + rr];
        }
        ridx += 1024;

        f32x4 sacc[4] = {};
#pragma unroll
        for (int cf = 0; cf < 4; ++cf) {
            bf16x8 kf0 = *(const bf16x8*)(Ks[cur] + koff[cf]);
            sacc[cf] = __builtin_amdgcn_mfma_f32_16x16x32_bf16(qf0, kf0, sacc[cf], 0, 0, 0);
            bf16x8 kf1 = *(const bf16x8*)(Ks[cur] + (koff[cf] ^ 32));
            sacc[cf] = __builtin_amdgcn_mfma_f32_16x16x32_bf16(qf1, kf1, sacc[cf], 0, 0, 0);
        }
#pragma unroll
        for (int cf = 0; cf < 4; ++cf)
#pragma unroll
            for (int rr = 0; rr < 4; ++rr)
                att[cf][rr] += exp2f(sacc[cf][rr] * LOG2E - m2r[rr]) * lir[rr];

        WAIT_VM0();    // next head's K staged
        BAR();         // all waves done reading Ks[cur]
        cur ^= 1;
    }

#pragma unroll
    for (int cf = 0; cf < 4; ++cf)
#pragma unroll
        for (int rr = 0; rr < 4; ++rr) {
            int row = q0 + wv * 16 + lg * 4 + rr;
            int col = kv0 + cf * 16 + lr;
            attnOut[((size_t)b * 1024 + row) * 2048 + col] = att[cf][rr] * 0.0625f;
        }
}

// ---------------------------------------------------------------------------
// launch
// ---------------------------------------------------------------------------
extern "C" void kernel_launch(void* const* d_in, const int* in_sizes, int n_in,
                              void* d_out, int out_size, void* d_ws, size_t ws_size,
                              hipStream_t stream)
{
    const float* x_cond  = (const float*)d_in[0];
    const float* x_query = (const float*)d_in[1];
    const float* tok     = (const float*)d_in[2];
    const float* w_in    = (const float*)d_in[3];
    const float* b_in    = (const float*)d_in[4];
    const float* w_out   = (const float*)d_in[5];
    const float* b_out   = (const float*)d_in[6];

    float* fused = (float*)d_out;
    float* attn  = (float*)d_out + 2097152;

    unsigned short* ws = (unsigned short*)d_ws;
    unsigned short* Aq   = ws;              // 2M halves
    unsigned short* Ac   = Aq   + 2097152;  // 4M
    unsigned short* Wb   = Ac   + 4194304;  // 4M (wq,wk,wv,wo rows)
    unsigned short* Qh   = Wb   + 4194304;  // 2M
    unsigned short* Kh   = Qh   + 2097152;  // 4M
    unsigned short* Vh   = Kh   + 4194304;  // 4M
    unsigned short* Vt   = Vh   + 4194304;  // 4M
    unsigned short* ctxb = Vt   + 4194304;  // 2M
    float* m2b = (float*)(ctxb + 2097152);  // 32768
    float* lib = m2b + 32768;               // 32768

    // 1. bf16 conversions (tok[1] -> query, tok[0] -> cond)
    conv_bf16<<<1024, 256, 0, stream>>>(x_query, tok + 1024, Aq, 262144);
    conv_bf16<<<2048, 256, 0, stream>>>(x_cond,  tok,        Ac, 524288);
    conv_bf16<<<1536, 256, 0, stream>>>(w_in,  nullptr, Wb,           393216);
    conv_bf16<<< 512, 256, 0, stream>>>(w_out, nullptr, Wb + 3145728, 131072);

    // 2. projections (Q scaled by 0.125 = softmax scale, folded)
    gemm_mfma<<<dim3(8, 16), 256, 0, stream>>>(Aq, Wb,           b_in,        Qh, 10, 0.125f, 1);
    gemm_mfma<<<dim3(8, 32), 256, 0, stream>>>(Ac, Wb + 1048576, b_in + 1024, Kh, 11, 1.0f,   1);
    gemm_mfma<<<dim3(8, 32), 256, 0, stream>>>(Ac, Wb + 2097152, b_in + 2048, Vh, 11, 1.0f,   1);

    // 3. V transpose -> [bh][64][2048]
    transpose_v<<<dim3(32, 32), 256, 0, stream>>>(Vh, Vt);

    // 4. attention
    flash_fwd<<<dim3(16, 16, 2), 256, 0, stream>>>(Qh, Kh, Vt, ctxb, m2b, lib);
    attn_mean_mfma<<<dim3(32, 16, 2), 256, 0, stream>>>(Qh, Kh, m2b, lib, attn);

    // 5. output projection (f32 out)
    gemm_mfma<<<dim3(8, 16), 256, 0, stream>>>(ctxb, Wb + 3145728, b_out, fused, 0, 1.0f, 0);
}

// Round 7
// 256.769 us; speedup vs baseline: 15.4364x; 1.1874x over previous
//
#include <hip/hip_runtime.h>
#include <hip/hip_bf16.h>
#include <cstddef>
#include <cstdint>

// B=2, Lq=1024, Lkv=2048, D=1024, H=16, hd=64.  All MFMA = 16x16x32 bf16.

typedef float  f32x4  __attribute__((ext_vector_type(4)));
typedef short  bf16x8 __attribute__((ext_vector_type(8)));
typedef unsigned short u16x8 __attribute__((ext_vector_type(8)));
typedef __attribute__((address_space(1))) const void gvoid;
typedef __attribute__((address_space(3))) void lvoid;
#define GLD16(g, l) __builtin_amdgcn_global_load_lds((gvoid*)(g), (lvoid*)(l), 16, 0, 0)
#define WAIT_VM0()   asm volatile("s_waitcnt vmcnt(0)" ::: "memory")
#define WAIT_LGKM0() asm volatile("s_waitcnt lgkmcnt(0)" ::: "memory")
#define BAR() __builtin_amdgcn_s_barrier()
#define LOG2E 1.4426950408889634f

static __device__ __forceinline__ unsigned short f2bf(float f) {
    union { float f; unsigned u; } v; v.f = f;
    unsigned r = v.u + 0x7fff + ((v.u >> 16) & 1);   // RNE
    return (unsigned short)(r >> 16);
}

// ---------------------------------------------------------------------------
// f32 (+ optional per-column tok add, cols mod 1024) -> bf16, 8 elems/thread
// ---------------------------------------------------------------------------
__global__ __launch_bounds__(256)
void conv_bf16(const float* __restrict__ x, const float* __restrict__ tok,
               unsigned short* __restrict__ out, int n8)
{
    int i = blockIdx.x * 256 + threadIdx.x;
    if (i >= n8) return;
    const float4* src = (const float4*)x + (size_t)i * 2;
    float4 a = src[0], b = src[1];
    if (tok) {
        int col = (i * 8) & 1023;
        const float4* tp = (const float4*)(tok + col);
        float4 t0 = tp[0], t1 = tp[1];
        a.x += t0.x; a.y += t0.y; a.z += t0.z; a.w += t0.w;
        b.x += t1.x; b.y += t1.y; b.z += t1.z; b.w += t1.w;
    }
    u16x8 r;
    r[0] = f2bf(a.x); r[1] = f2bf(a.y); r[2] = f2bf(a.z); r[3] = f2bf(a.w);
    r[4] = f2bf(b.x); r[5] = f2bf(b.y); r[6] = f2bf(b.z); r[7] = f2bf(b.w);
    ((u16x8*)out)[i] = r;
}

// ---------------------------------------------------------------------------
// Merged QKV MFMA GEMM: one dispatch, grid (8, 80): y<16 Q, y<48 K, else V.
// 128x128 tile, BK=64, 4 waves, 4x4 frags.  Head-layout bf16 store.
// ---------------------------------------------------------------------------
__global__ __launch_bounds__(256)
void gemm_qkv(const unsigned short* __restrict__ Aq,
              const unsigned short* __restrict__ Ac,
              const unsigned short* __restrict__ W,
              const float* __restrict__ bias,
              unsigned short* __restrict__ Qh,
              unsigned short* __restrict__ Kh,
              unsigned short* __restrict__ Vh)
{
    __shared__ unsigned short As[128 * 64];
    __shared__ unsigned short Bs[128 * 64];
    const int t  = threadIdx.x;
    const int wv = t >> 6, ln = t & 63;
    const int wr = wv >> 1, wc = wv & 1;
    const int lr = ln & 15, lg = ln >> 4;
    const int y = blockIdx.y;

    const unsigned short* A; const unsigned short* Wp; const float* bs;
    unsigned short* Y; int Lshift, m0; float scale;
    if (y < 16)      { A = Aq; m0 = y * 128;        Wp = W;           bs = bias;        Y = Qh; Lshift = 10; scale = 0.125f; }
    else if (y < 48) { A = Ac; m0 = (y - 16) * 128; Wp = W + 1048576; bs = bias + 1024; Y = Kh; Lshift = 11; scale = 1.0f; }
    else             { A = Ac; m0 = (y - 48) * 128; Wp = W + 2097152; bs = bias + 2048; Y = Vh; Lshift = 11; scale = 1.0f; }
    const int n0 = blockIdx.x * 128;

    f32x4 acc[4][4] = {};

    for (int k0 = 0; k0 < 1024; k0 += 64) {
        __syncthreads();
#pragma unroll
        for (int ia = 0; ia < 4; ++ia) {
            int idx = ia * 256 + t;
            int row = idx >> 3, c = idx & 7;
            int sw = (c ^ (row & 7)) * 8;
            GLD16(A  + (size_t)(m0 + row) * 1024 + k0 + sw, As + idx * 8);
            GLD16(Wp + (size_t)(n0 + row) * 1024 + k0 + sw, Bs + idx * 8);
        }
        WAIT_VM0();
        __syncthreads();
#pragma unroll
        for (int ks = 0; ks < 2; ++ks) {
            bf16x8 af[4], bf[4];
#pragma unroll
            for (int i = 0; i < 4; ++i) {
                int rowA = wr * 64 + i * 16 + lr;
                af[i] = *(const bf16x8*)(As + rowA * 64 + (((ks * 4 + lg) ^ (rowA & 7)) * 8));
                int rowB = wc * 64 + i * 16 + lr;
                bf[i] = *(const bf16x8*)(Bs + rowB * 64 + (((ks * 4 + lg) ^ (rowB & 7)) * 8));
            }
#pragma unroll
            for (int i = 0; i < 4; ++i)
#pragma unroll
                for (int j = 0; j < 4; ++j)
                    acc[i][j] = __builtin_amdgcn_mfma_f32_16x16x32_bf16(af[i], bf[j], acc[i][j], 0, 0, 0);
        }
    }

#pragma unroll
    for (int i = 0; i < 4; ++i) {
        int rb = m0 + wr * 64 + i * 16 + lg * 4;
#pragma unroll
        for (int j = 0; j < 4; ++j) {
            int col = n0 + wc * 64 + j * 16 + lr;
            float bv = bs[col];
#pragma unroll
            for (int rr = 0; rr < 4; ++rr) {
                float v = (acc[i][j][rr] + bv) * scale;
                int r = rb + rr;
                int b = r >> Lshift, l = r & ((1 << Lshift) - 1);
                int hh = col >> 6, d = col & 63;
                Y[((((size_t)b * 16 + hh) << Lshift) + l) * 64 + d] = f2bf(v);
            }
        }
    }
}

// ---------------------------------------------------------------------------
// MFMA GEMM (out-projection): f32 flat store.
// ---------------------------------------------------------------------------
__global__ __launch_bounds__(256)
void gemm_mfma(const unsigned short* __restrict__ A,
               const unsigned short* __restrict__ W,
               const float* __restrict__ bias,
               float* __restrict__ Y)
{
    __shared__ unsigned short As[128 * 64];
    __shared__ unsigned short Bs[128 * 64];
    const int t  = threadIdx.x;
    const int wv = t >> 6, ln = t & 63;
    const int wr = wv >> 1, wc = wv & 1;
    const int lr = ln & 15, lg = ln >> 4;
    const int m0 = blockIdx.y * 128, n0 = blockIdx.x * 128;

    f32x4 acc[4][4] = {};

    for (int k0 = 0; k0 < 1024; k0 += 64) {
        __syncthreads();
#pragma unroll
        for (int ia = 0; ia < 4; ++ia) {
            int idx = ia * 256 + t;
            int row = idx >> 3, c = idx & 7;
            int sw = (c ^ (row & 7)) * 8;
            GLD16(A + (size_t)(m0 + row) * 1024 + k0 + sw, As + idx * 8);
            GLD16(W + (size_t)(n0 + row) * 1024 + k0 + sw, Bs + idx * 8);
        }
        WAIT_VM0();
        __syncthreads();
#pragma unroll
        for (int ks = 0; ks < 2; ++ks) {
            bf16x8 af[4], bf[4];
#pragma unroll
            for (int i = 0; i < 4; ++i) {
                int rowA = wr * 64 + i * 16 + lr;
                af[i] = *(const bf16x8*)(As + rowA * 64 + (((ks * 4 + lg) ^ (rowA & 7)) * 8));
                int rowB = wc * 64 + i * 16 + lr;
                bf[i] = *(const bf16x8*)(Bs + rowB * 64 + (((ks * 4 + lg) ^ (rowB & 7)) * 8));
            }
#pragma unroll
            for (int i = 0; i < 4; ++i)
#pragma unroll
                for (int j = 0; j < 4; ++j)
                    acc[i][j] = __builtin_amdgcn_mfma_f32_16x16x32_bf16(af[i], bf[j], acc[i][j], 0, 0, 0);
        }
    }

#pragma unroll
    for (int i = 0; i < 4; ++i) {
        int rb = m0 + wr * 64 + i * 16 + lg * 4;
#pragma unroll
        for (int j = 0; j < 4; ++j) {
            int col = n0 + wc * 64 + j * 16 + lr;
            float bv = bias[col];
#pragma unroll
            for (int rr = 0; rr < 4; ++rr)
                Y[(size_t)(rb + rr) * 1024 + col] = acc[i][j][rr] + bv;
        }
    }
}

// ---------------------------------------------------------------------------
// Vh[b][h][2048][64] -> Vt[b][h][64][2048]  (bf16 transpose via LDS)
// ---------------------------------------------------------------------------
__global__ __launch_bounds__(256)
void transpose_v(const unsigned short* __restrict__ Vh, unsigned short* __restrict__ Vt)
{
    __shared__ unsigned short L[64 * 72];
    const int t = threadIdx.x;
    const int kt = blockIdx.x;   // 0..31 kv tile
    const int bh = blockIdx.y;   // 0..31
    const unsigned short* src = Vh + ((size_t)bh * 2048 + kt * 64) * 64;
#pragma unroll
    for (int i = 0; i < 2; ++i) {
        int idx = i * 256 + t;
        int kv = idx >> 3, c = idx & 7;
        *(bf16x8*)(L + kv * 72 + c * 8) = *(const bf16x8*)(src + kv * 64 + c * 8);
    }
    __syncthreads();
#pragma unroll
    for (int i = 0; i < 2; ++i) {
        int idx = i * 256 + t;
        int d = idx >> 3, ck = idx & 7;
        u16x8 r;
#pragma unroll
        for (int j = 0; j < 8; ++j) r[j] = L[(ck * 8 + j) * 72 + d];
        *(u16x8*)(Vt + ((size_t)bh * 64 + d) * 2048 + kt * 64 + ck * 8) = r;
    }
}

// ---------------------------------------------------------------------------
// Flash attention with SWAPPED QK^T (S^T = mfma(K,Q)): each lane owns ONE
// q row (= lr); row max/sum are in-register trees + 2 shfl_xor (16,32).
// P packed to LDS as b32 pairs (intra-wave only -> no barrier), read back as
// PV A-frags.  One barrier per KV tile; K/V double-buffered global_load_lds.
// ---------------------------------------------------------------------------
__global__ __launch_bounds__(256)
void flash_fwd(const unsigned short* __restrict__ Q,
               const unsigned short* __restrict__ K,
               const unsigned short* __restrict__ Vt,
               unsigned short* __restrict__ ctx,
               float* __restrict__ m2Out, float* __restrict__ linvOut)
{
    __shared__ unsigned short Ks[2][4096];
    __shared__ unsigned short Vs[2][4096];
    __shared__ unsigned int   Ps32[64 * 36];   // P rows stride 36 u32 = 72 halves
    const int t  = threadIdx.x;
    const int wv = t >> 6, ln = t & 63;
    const int lr = ln & 15, lg = ln >> 4;
    const int qt = blockIdx.x, h = blockIdx.y, b = blockIdx.z;
    const int bh = b * 16 + h;
    const int q0 = qt * 64;

    // staging map: 2 x 16B chunks per thread per matrix
    const int i0 = t, i1 = 256 + t;
    const int r0 = i0 >> 3, c0 = i0 & 7, sw0 = (c0 ^ (r0 & 7)) * 8;
    const int r1 = i1 >> 3, c1 = i1 & 7, sw1 = (c1 ^ (r1 & 7)) * 8;
    const int l0 = i0 * 8, l1 = i1 * 8;
    const int gk0 = r0 * 64 + sw0,   gk1 = r1 * 64 + sw1;
    const int gv0 = r0 * 2048 + sw0, gv1 = r1 * 2048 + sw1;

    // fragment offsets (shared by K as A-operand and V as B-operand)
    int koff[4];
#pragma unroll
    for (int cf = 0; cf < 4; ++cf)
        koff[cf] = (cf * 16 + lr) * 64 + ((lg ^ (lr & 7)) * 8);
    const int pw32 = (wv * 16 + lr) * 36 + lg * 2;   // + cf*8 + rp
    const int prH  = (wv * 16 + lr) * 72 + lg * 8;   // + kvs*32

    bf16x8 qf[2];
    {
        const unsigned short* qp = Q + ((size_t)bh * 1024 + q0 + wv * 16 + lr) * 64 + lg * 8;
        qf[0] = *(const bf16x8*)qp;
        qf[1] = *(const bf16x8*)(qp + 32);
    }

    f32x4 cacc[4] = {};
    float m2 = -1e30f, lsum = 0.f;   // per-lane: q row = q0 + wv*16 + lr

    const unsigned short* kp = K  + (size_t)bh * 2048 * 64;
    const unsigned short* vp = Vt + (size_t)bh * 64 * 2048;

    // prologue: stage tile 0 into buf 0
    GLD16(kp + gk0, &Ks[0][l0]); GLD16(kp + gk1, &Ks[0][l1]);
    GLD16(vp + gv0, &Vs[0][l0]); GLD16(vp + gv1, &Vs[0][l1]);
    kp += 4096; vp += 64;
    WAIT_VM0();
    BAR();

    int cur = 0;
    for (int tile = 0; tile < 32; ++tile) {
        if (tile < 31) {   // stage next tile (stays in flight through compute)
            GLD16(kp + gk0, &Ks[cur ^ 1][l0]); GLD16(kp + gk1, &Ks[cur ^ 1][l1]);
            GLD16(vp + gv0, &Vs[cur ^ 1][l0]); GLD16(vp + gv1, &Vs[cur ^ 1][l1]);
            kp += 4096; vp += 64;
        }

        // S^T = K Q^T : sacc[cf][rr] = S[kv = cf*16+lg*4+rr][q = lr]
        f32x4 sacc[4] = {};
#pragma unroll
        for (int cf = 0; cf < 4; ++cf) {
            bf16x8 kf0 = *(const bf16x8*)(Ks[cur] + koff[cf]);
            sacc[cf] = __builtin_amdgcn_mfma_f32_16x16x32_bf16(kf0, qf[0], sacc[cf], 0, 0, 0);
            bf16x8 kf1 = *(const bf16x8*)(Ks[cur] + (koff[cf] ^ 32));
            sacc[cf] = __builtin_amdgcn_mfma_f32_16x16x32_bf16(kf1, qf[1], sacc[cf], 0, 0, 0);
        }

        // row max: in-register tree over 16 + 2 shfl (xor16, xor32)
        float rm;
        {
            float a0 = fmaxf(fmaxf(sacc[0][0], sacc[0][1]), fmaxf(sacc[0][2], sacc[0][3]));
            float a1 = fmaxf(fmaxf(sacc[1][0], sacc[1][1]), fmaxf(sacc[1][2], sacc[1][3]));
            float a2 = fmaxf(fmaxf(sacc[2][0], sacc[2][1]), fmaxf(sacc[2][2], sacc[2][3]));
            float a3 = fmaxf(fmaxf(sacc[3][0], sacc[3][1]), fmaxf(sacc[3][2], sacc[3][3]));
            rm = fmaxf(fmaxf(a0, a1), fmaxf(a2, a3));
        }
        rm = fmaxf(rm, __shfl_xor(rm, 16, 64));
        rm = fmaxf(rm, __shfl_xor(rm, 32, 64));
        rm *= LOG2E;

        if (__any(rm > m2)) {          // rescale only when some row's max grew
            float nm = fmaxf(m2, rm);
            float sc = exp2f(m2 - nm);
            m2 = nm;
            lsum *= sc;
            float scB[4];
#pragma unroll
            for (int rr = 0; rr < 4; ++rr)
                scB[rr] = __shfl(sc, (ln & 48) | (lg * 4 + rr), 64);
#pragma unroll
            for (int df = 0; df < 4; ++df)
#pragma unroll
                for (int rr = 0; rr < 4; ++rr) cacc[df][rr] *= scB[rr];
        }

        // p = exp2(s*log2e - m2); pack pairs -> 8 ds_write_b32 (own rows only)
        float p[4][4];
#pragma unroll
        for (int cf = 0; cf < 4; ++cf)
#pragma unroll
            for (int rr = 0; rr < 4; ++rr)
                p[cf][rr] = exp2f(fmaf(sacc[cf][rr], LOG2E, -m2));
#pragma unroll
        for (int cf = 0; cf < 4; ++cf) {
            Ps32[pw32 + cf * 8 + 0] = (unsigned)f2bf(p[cf][0]) | ((unsigned)f2bf(p[cf][1]) << 16);
            Ps32[pw32 + cf * 8 + 1] = (unsigned)f2bf(p[cf][2]) | ((unsigned)f2bf(p[cf][3]) << 16);
        }

        // row sum while the writes drain
        float rs;
        {
            float s0 = (p[0][0] + p[0][1]) + (p[0][2] + p[0][3]);
            float s1 = (p[1][0] + p[1][1]) + (p[1][2] + p[1][3]);
            float s2 = (p[2][0] + p[2][1]) + (p[2][2] + p[2][3]);
            float s3 = (p[3][0] + p[3][1]) + (p[3][2] + p[3][3]);
            rs = (s0 + s1) + (s2 + s3);
        }
        rs += __shfl_xor(rs, 16, 64);
        rs += __shfl_xor(rs, 32, 64);
        lsum += rs;

        WAIT_LGKM0();                  // P writes visible to own wave (no barrier)

        // ctx += P V
#pragma unroll
        for (int kvs = 0; kvs < 2; ++kvs) {
            bf16x8 pf = *(const bf16x8*)((const unsigned short*)Ps32 + prH + kvs * 32);
#pragma unroll
            for (int df = 0; df < 4; ++df) {
                bf16x8 vf = *(const bf16x8*)(Vs[cur] + (koff[df] ^ (kvs * 32)));
                cacc[df] = __builtin_amdgcn_mfma_f32_16x16x32_bf16(pf, vf, cacc[df], 0, 0, 0);
            }
        }
        WAIT_VM0();                    // next tile's staging complete
        BAR();                         // all waves done reading buf[cur]
        cur ^= 1;
    }

    float inv = 1.f / lsum;
    float invB[4];
#pragma unroll
    for (int rr = 0; rr < 4; ++rr)
        invB[rr] = __shfl(inv, (ln & 48) | (lg * 4 + rr), 64);
#pragma unroll
    for (int df = 0; df < 4; ++df) {
#pragma unroll
        for (int rr = 0; rr < 4; ++rr) {
            int row = q0 + wv * 16 + lg * 4 + rr;
            int col = h * 64 + df * 16 + lr;
            ctx[((size_t)b * 1024 + row) * 1024 + col] = f2bf(cacc[df][rr] * invB[rr]);
        }
    }
    if (lg == 0) {
        size_t idx = (size_t)bh * 1024 + q0 + wv * 16 + lr;
        m2Out[idx]   = m2;
        linvOut[idx] = inv;
    }
}

// ---------------------------------------------------------------------------
// attn-mean: block per (b, 64q, 64kv); loops 16 heads with double-buffered
// K staging. S by MFMA identical to flash.
// ---------------------------------------------------------------------------
__global__ __launch_bounds__(256)
void attn_mean_mfma(const unsigned short* __restrict__ Q,
                    const unsigned short* __restrict__ K,
                    const float* __restrict__ m2In, const float* __restrict__ linvIn,
                    float* __restrict__ attnOut)
{
    __shared__ unsigned short Ks[2][64 * 64];
    const int t  = threadIdx.x;
    const int wv = t >> 6, ln = t & 63;
    const int lr = ln & 15, lg = ln >> 4;
    const int kt = blockIdx.x, qt = blockIdx.y, b = blockIdx.z;
    const int q0 = qt * 64, kv0 = kt * 64;

    const int i0 = t, i1 = 256 + t;
    const int r0 = i0 >> 3, c0 = i0 & 7, sw0 = (c0 ^ (r0 & 7)) * 8;
    const int r1 = i1 >> 3, c1 = i1 & 7, sw1 = (c1 ^ (r1 & 7)) * 8;
    const int l0 = i0 * 8, l1 = i1 * 8;
    const int gk0 = r0 * 64 + sw0, gk1 = r1 * 64 + sw1;

    int koff[4];
#pragma unroll
    for (int cf = 0; cf < 4; ++cf)
        koff[cf] = (cf * 16 + lr) * 64 + ((lg ^ (lr & 7)) * 8);

    const unsigned short* kp = K + ((size_t)(b * 16) * 2048 + kv0) * 64;
    const unsigned short* qp = Q + ((size_t)(b * 16) * 1024 + q0 + wv * 16 + lr) * 64 + lg * 8;
    size_t ridx = (size_t)(b * 16) * 1024 + q0 + wv * 16 + lg * 4;

    float att[4][4] = {};

    // prologue: stage head 0
    GLD16(kp + gk0, &Ks[0][l0]); GLD16(kp + gk1, &Ks[0][l1]);
    kp += 131072;
    WAIT_VM0();
    BAR();

    int cur = 0;
    for (int h = 0; h < 16; ++h) {
        if (h < 15) {
            GLD16(kp + gk0, &Ks[cur ^ 1][l0]); GLD16(kp + gk1, &Ks[cur ^ 1][l1]);
            kp += 131072;
        }
        bf16x8 qf0 = *(const bf16x8*)qp;
        bf16x8 qf1 = *(const bf16x8*)(qp + 32);
        qp += 65536;
        float m2r[4], lir[4];
#pragma unroll
        for (int rr = 0; rr < 4; ++rr) {
            m2r[rr] = m2In[ridx + rr];
            lir[rr] = linvIn[ridx + rr];
        }
        ridx += 1024;

        f32x4 sacc[4] = {};
#pragma unroll
        for (int cf = 0; cf < 4; ++cf) {
            bf16x8 kf0 = *(const bf16x8*)(Ks[cur] + koff[cf]);
            sacc[cf] = __builtin_amdgcn_mfma_f32_16x16x32_bf16(qf0, kf0, sacc[cf], 0, 0, 0);
            bf16x8 kf1 = *(const bf16x8*)(Ks[cur] + (koff[cf] ^ 32));
            sacc[cf] = __builtin_amdgcn_mfma_f32_16x16x32_bf16(qf1, kf1, sacc[cf], 0, 0, 0);
        }
#pragma unroll
        for (int cf = 0; cf < 4; ++cf)
#pragma unroll
            for (int rr = 0; rr < 4; ++rr)
                att[cf][rr] += exp2f(sacc[cf][rr] * LOG2E - m2r[rr]) * lir[rr];

        WAIT_VM0();    // next head's K staged
        BAR();         // all waves done reading Ks[cur]
        cur ^= 1;
    }

#pragma unroll
    for (int cf = 0; cf < 4; ++cf)
#pragma unroll
        for (int rr = 0; rr < 4; ++rr) {
            int row = q0 + wv * 16 + lg * 4 + rr;
            int col = kv0 + cf * 16 + lr;
            attnOut[((size_t)b * 1024 + row) * 2048 + col] = att[cf][rr] * 0.0625f;
        }
}

// ---------------------------------------------------------------------------
// launch
// ---------------------------------------------------------------------------
extern "C" void kernel_launch(void* const* d_in, const int* in_sizes, int n_in,
                              void* d_out, int out_size, void* d_ws, size_t ws_size,
                              hipStream_t stream)
{
    const float* x_cond  = (const float*)d_in[0];
    const float* x_query = (const float*)d_in[1];
    const float* tok     = (const float*)d_in[2];
    const float* w_in    = (const float*)d_in[3];
    const float* b_in    = (const float*)d_in[4];
    const float* w_out   = (const float*)d_in[5];
    const float* b_out   = (const float*)d_in[6];

    float* fused = (float*)d_out;
    float* attn  = (float*)d_out + 2097152;

    unsigned short* ws = (unsigned short*)d_ws;
    unsigned short* Aq   = ws;              // 2M halves
    unsigned short* Ac   = Aq   + 2097152;  // 4M
    unsigned short* Wb   = Ac   + 4194304;  // 4M (wq,wk,wv,wo rows)
    unsigned short* Qh   = Wb   + 4194304;  // 2M
    unsigned short* Kh   = Qh   + 2097152;  // 4M
    unsigned short* Vh   = Kh   + 4194304;  // 4M
    unsigned short* Vt   = Vh   + 4194304;  // 4M
    unsigned short* ctxb = Vt   + 4194304;  // 2M
    float* m2b = (float*)(ctxb + 2097152);  // 32768
    float* lib = m2b + 32768;               // 32768

    // 1. bf16 conversions (tok[1] -> query, tok[0] -> cond)
    conv_bf16<<<1024, 256, 0, stream>>>(x_query, tok + 1024, Aq, 262144);
    conv_bf16<<<2048, 256, 0, stream>>>(x_cond,  tok,        Ac, 524288);
    conv_bf16<<<1536, 256, 0, stream>>>(w_in,  nullptr, Wb,           393216);
    conv_bf16<<< 512, 256, 0, stream>>>(w_out, nullptr, Wb + 3145728, 131072);

    // 2. merged Q/K/V projection (Q scaled by 0.125, folded)
    gemm_qkv<<<dim3(8, 80), 256, 0, stream>>>(Aq, Ac, Wb, b_in, Qh, Kh, Vh);

    // 3. V transpose -> [bh][64][2048]
    transpose_v<<<dim3(32, 32), 256, 0, stream>>>(Vh, Vt);

    // 4. attention
    flash_fwd<<<dim3(16, 16, 2), 256, 0, stream>>>(Qh, Kh, Vt, ctxb, m2b, lib);
    attn_mean_mfma<<<dim3(32, 16, 2), 256, 0, stream>>>(Qh, Kh, m2b, lib, attn);

    // 5. output projection (f32 out)
    gemm_mfma<<<dim3(8, 16), 256, 0, stream>>>(ctxb, Wb + 3145728, b_out, fused);
}

// Round 8
// 250.478 us; speedup vs baseline: 15.8241x; 1.0251x over previous
//
#include <hip/hip_runtime.h>
#include <hip/hip_bf16.h>
#include <cstddef>
#include <cstdint>

// B=2, Lq=1024, Lkv=2048, D=1024, H=16, hd=64.  All MFMA = 16x16x32 bf16.

typedef float  f32x4  __attribute__((ext_vector_type(4)));
typedef short  bf16x8 __attribute__((ext_vector_type(8)));
typedef unsigned short u16x8 __attribute__((ext_vector_type(8)));
typedef __attribute__((address_space(1))) const void gvoid;
typedef __attribute__((address_space(3))) void lvoid;
#define GLD16(g, l) __builtin_amdgcn_global_load_lds((gvoid*)(g), (lvoid*)(l), 16, 0, 0)
#define WAIT_VM0()   asm volatile("s_waitcnt vmcnt(0)" ::: "memory")
#define WAIT_LGKM0() asm volatile("s_waitcnt lgkmcnt(0)" ::: "memory")
#define BAR() __builtin_amdgcn_s_barrier()
#define LOG2E 1.4426950408889634f

static __device__ __forceinline__ unsigned short f2bf(float f) {
    union { float f; unsigned u; } v; v.f = f;
    unsigned r = v.u + 0x7fff + ((v.u >> 16) & 1);   // RNE
    return (unsigned short)(r >> 16);
}
static __device__ __forceinline__ float bf2f(unsigned short u) {
    union { unsigned u; float f; } v; v.u = (unsigned)u << 16; return v.f;
}

// ---------------------------------------------------------------------------
// f32 (+ optional per-column tok add, cols mod 1024) -> bf16, 8 elems/thread
// ---------------------------------------------------------------------------
__global__ __launch_bounds__(256)
void conv_bf16(const float* __restrict__ x, const float* __restrict__ tok,
               unsigned short* __restrict__ out, int n8)
{
    int i = blockIdx.x * 256 + threadIdx.x;
    if (i >= n8) return;
    const float4* src = (const float4*)x + (size_t)i * 2;
    float4 a = src[0], b = src[1];
    if (tok) {
        int col = (i * 8) & 1023;
        const float4* tp = (const float4*)(tok + col);
        float4 t0 = tp[0], t1 = tp[1];
        a.x += t0.x; a.y += t0.y; a.z += t0.z; a.w += t0.w;
        b.x += t1.x; b.y += t1.y; b.z += t1.z; b.w += t1.w;
    }
    u16x8 r;
    r[0] = f2bf(a.x); r[1] = f2bf(a.y); r[2] = f2bf(a.z); r[3] = f2bf(a.w);
    r[4] = f2bf(b.x); r[5] = f2bf(b.y); r[6] = f2bf(b.z); r[7] = f2bf(b.w);
    ((u16x8*)out)[i] = r;
}

// ---------------------------------------------------------------------------
// Merged QKV MFMA GEMM: one dispatch, grid (8, 80): y<16 Q, y<48 K, else V.
// ---------------------------------------------------------------------------
__global__ __launch_bounds__(256)
void gemm_qkv(const unsigned short* __restrict__ Aq,
              const unsigned short* __restrict__ Ac,
              const unsigned short* __restrict__ W,
              const float* __restrict__ bias,
              unsigned short* __restrict__ Qh,
              unsigned short* __restrict__ Kh,
              unsigned short* __restrict__ Vh)
{
    __shared__ unsigned short As[128 * 64];
    __shared__ unsigned short Bs[128 * 64];
    const int t  = threadIdx.x;
    const int wv = t >> 6, ln = t & 63;
    const int wr = wv >> 1, wc = wv & 1;
    const int lr = ln & 15, lg = ln >> 4;
    const int y = blockIdx.y;

    const unsigned short* A; const unsigned short* Wp; const float* bs;
    unsigned short* Y; int Lshift, m0; float scale;
    if (y < 16)      { A = Aq; m0 = y * 128;        Wp = W;           bs = bias;        Y = Qh; Lshift = 10; scale = 0.125f; }
    else if (y < 48) { A = Ac; m0 = (y - 16) * 128; Wp = W + 1048576; bs = bias + 1024; Y = Kh; Lshift = 11; scale = 1.0f; }
    else             { A = Ac; m0 = (y - 48) * 128; Wp = W + 2097152; bs = bias + 2048; Y = Vh; Lshift = 11; scale = 1.0f; }
    const int n0 = blockIdx.x * 128;

    f32x4 acc[4][4] = {};

    for (int k0 = 0; k0 < 1024; k0 += 64) {
        __syncthreads();
#pragma unroll
        for (int ia = 0; ia < 4; ++ia) {
            int idx = ia * 256 + t;
            int row = idx >> 3, c = idx & 7;
            int sw = (c ^ (row & 7)) * 8;
            GLD16(A  + (size_t)(m0 + row) * 1024 + k0 + sw, As + idx * 8);
            GLD16(Wp + (size_t)(n0 + row) * 1024 + k0 + sw, Bs + idx * 8);
        }
        WAIT_VM0();
        __syncthreads();
#pragma unroll
        for (int ks = 0; ks < 2; ++ks) {
            bf16x8 af[4], bf[4];
#pragma unroll
            for (int i = 0; i < 4; ++i) {
                int rowA = wr * 64 + i * 16 + lr;
                af[i] = *(const bf16x8*)(As + rowA * 64 + (((ks * 4 + lg) ^ (rowA & 7)) * 8));
                int rowB = wc * 64 + i * 16 + lr;
                bf[i] = *(const bf16x8*)(Bs + rowB * 64 + (((ks * 4 + lg) ^ (rowB & 7)) * 8));
            }
#pragma unroll
            for (int i = 0; i < 4; ++i)
#pragma unroll
                for (int j = 0; j < 4; ++j)
                    acc[i][j] = __builtin_amdgcn_mfma_f32_16x16x32_bf16(af[i], bf[j], acc[i][j], 0, 0, 0);
        }
    }

#pragma unroll
    for (int i = 0; i < 4; ++i) {
        int rb = m0 + wr * 64 + i * 16 + lg * 4;
#pragma unroll
        for (int j = 0; j < 4; ++j) {
            int col = n0 + wc * 64 + j * 16 + lr;
            float bv = bs[col];
#pragma unroll
            for (int rr = 0; rr < 4; ++rr) {
                float v = (acc[i][j][rr] + bv) * scale;
                int r = rb + rr;
                int b = r >> Lshift, l = r & ((1 << Lshift) - 1);
                int hh = col >> 6, d = col & 63;
                Y[((((size_t)b * 16 + hh) << Lshift) + l) * 64 + d] = f2bf(v);
            }
        }
    }
}

// ---------------------------------------------------------------------------
// MFMA GEMM (out-projection): f32 flat store.
// ---------------------------------------------------------------------------
__global__ __launch_bounds__(256)
void gemm_mfma(const unsigned short* __restrict__ A,
               const unsigned short* __restrict__ W,
               const float* __restrict__ bias,
               float* __restrict__ Y)
{
    __shared__ unsigned short As[128 * 64];
    __shared__ unsigned short Bs[128 * 64];
    const int t  = threadIdx.x;
    const int wv = t >> 6, ln = t & 63;
    const int wr = wv >> 1, wc = wv & 1;
    const int lr = ln & 15, lg = ln >> 4;
    const int m0 = blockIdx.y * 128, n0 = blockIdx.x * 128;

    f32x4 acc[4][4] = {};

    for (int k0 = 0; k0 < 1024; k0 += 64) {
        __syncthreads();
#pragma unroll
        for (int ia = 0; ia < 4; ++ia) {
            int idx = ia * 256 + t;
            int row = idx >> 3, c = idx & 7;
            int sw = (c ^ (row & 7)) * 8;
            GLD16(A + (size_t)(m0 + row) * 1024 + k0 + sw, As + idx * 8);
            GLD16(W + (size_t)(n0 + row) * 1024 + k0 + sw, Bs + idx * 8);
        }
        WAIT_VM0();
        __syncthreads();
#pragma unroll
        for (int ks = 0; ks < 2; ++ks) {
            bf16x8 af[4], bf[4];
#pragma unroll
            for (int i = 0; i < 4; ++i) {
                int rowA = wr * 64 + i * 16 + lr;
                af[i] = *(const bf16x8*)(As + rowA * 64 + (((ks * 4 + lg) ^ (rowA & 7)) * 8));
                int rowB = wc * 64 + i * 16 + lr;
                bf[i] = *(const bf16x8*)(Bs + rowB * 64 + (((ks * 4 + lg) ^ (rowB & 7)) * 8));
            }
#pragma unroll
            for (int i = 0; i < 4; ++i)
#pragma unroll
                for (int j = 0; j < 4; ++j)
                    acc[i][j] = __builtin_amdgcn_mfma_f32_16x16x32_bf16(af[i], bf[j], acc[i][j], 0, 0, 0);
        }
    }

#pragma unroll
    for (int i = 0; i < 4; ++i) {
        int rb = m0 + wr * 64 + i * 16 + lg * 4;
#pragma unroll
        for (int j = 0; j < 4; ++j) {
            int col = n0 + wc * 64 + j * 16 + lr;
            float bv = bias[col];
#pragma unroll
            for (int rr = 0; rr < 4; ++rr)
                Y[(size_t)(rb + rr) * 1024 + col] = acc[i][j][rr] + bv;
        }
    }
}

// ---------------------------------------------------------------------------
// Vh[b][h][2048][64] -> Vt[b][h][64][2048]  (bf16 transpose via LDS)
// ---------------------------------------------------------------------------
__global__ __launch_bounds__(256)
void transpose_v(const unsigned short* __restrict__ Vh, unsigned short* __restrict__ Vt)
{
    __shared__ unsigned short L[64 * 72];
    const int t = threadIdx.x;
    const int kt = blockIdx.x;   // 0..31 kv tile
    const int bh = blockIdx.y;   // 0..31
    const unsigned short* src = Vh + ((size_t)bh * 2048 + kt * 64) * 64;
#pragma unroll
    for (int i = 0; i < 2; ++i) {
        int idx = i * 256 + t;
        int kv = idx >> 3, c = idx & 7;
        *(bf16x8*)(L + kv * 72 + c * 8) = *(const bf16x8*)(src + kv * 64 + c * 8);
    }
    __syncthreads();
#pragma unroll
    for (int i = 0; i < 2; ++i) {
        int idx = i * 256 + t;
        int d = idx >> 3, ck = idx & 7;
        u16x8 r;
#pragma unroll
        for (int j = 0; j < 8; ++j) r[j] = L[(ck * 8 + j) * 72 + d];
        *(u16x8*)(Vt + ((size_t)bh * 64 + d) * 2048 + kt * 64 + ck * 8) = r;
    }
}

// ---------------------------------------------------------------------------
// Flash attention, swapped QK^T, KV-split C=2 (chunk = blockIdx.y, 1024 kv).
// Grid 1024 blocks = 4/CU; LDS exactly 40960 B (Ps stride-64 + XOR-quad
// swizzle) so 4 blocks/CU fit.  Writes UNnormalized partial ctx (bf16) and
// per-row (m2, lsum) for a 2-way combine pass.
// ---------------------------------------------------------------------------
__global__ __launch_bounds__(256)
void flash_fwd(const unsigned short* __restrict__ Q,
               const unsigned short* __restrict__ K,
               const unsigned short* __restrict__ Vt,
               unsigned short* __restrict__ pctx,   // [2][32768][64] bf16
               float* __restrict__ pm,              // [2][32768]
               float* __restrict__ pl)              // [2][32768]
{
    __shared__ unsigned short Ks[2][4096];
    __shared__ unsigned short Vs[2][4096];
    __shared__ unsigned int   Ps32[64 * 32];   // stride 32 u32/row, XOR-swizzled
    const int t  = threadIdx.x;
    const int wv = t >> 6, ln = t & 63;
    const int lr = ln & 15, lg = ln >> 4;
    const int qt = blockIdx.x, ch = blockIdx.y, bh = blockIdx.z;
    const int q0 = qt * 64;

    // staging map: 2 x 16B chunks per thread per matrix
    const int i0 = t, i1 = 256 + t;
    const int r0 = i0 >> 3, c0 = i0 & 7, sw0 = (c0 ^ (r0 & 7)) * 8;
    const int r1 = i1 >> 3, c1 = i1 & 7, sw1 = (c1 ^ (r1 & 7)) * 8;
    const int l0 = i0 * 8, l1 = i1 * 8;
    const int gk0 = r0 * 64 + sw0,   gk1 = r1 * 64 + sw1;
    const int gv0 = r0 * 2048 + sw0, gv1 = r1 * 2048 + sw1;

    // fragment offsets (K as A-operand, V as B-operand share formula)
    int koff[4];
#pragma unroll
    for (int cf = 0; cf < 4; ++cf)
        koff[cf] = (cf * 16 + lr) * 64 + ((lg ^ (lr & 7)) * 8);
    const int pwB = (wv * 16 + lr) * 32;      // u32 row base (own row)
    const int pxr = (lr & 7) * 4;             // XOR key, u32-word domain
    const int prq0 = (wv * 16 + lr) * 64 + ((lg ^ (lr & 7)) * 8);        // kvs=0
    const int prq1 = (wv * 16 + lr) * 64 + (((4 + lg) ^ (lr & 7)) * 8);  // kvs=1

    bf16x8 qf[2];
    {
        const unsigned short* qp = Q + ((size_t)bh * 1024 + q0 + wv * 16 + lr) * 64 + lg * 8;
        qf[0] = *(const bf16x8*)qp;
        qf[1] = *(const bf16x8*)(qp + 32);
    }

    f32x4 cacc[4] = {};
    float m2 = -1e30f, lsum = 0.f;   // per-lane: q row = q0 + wv*16 + lr

    const unsigned short* kp = K  + ((size_t)bh * 2048 + ch * 1024) * 64;
    const unsigned short* vp = Vt + (size_t)bh * 64 * 2048 + ch * 1024;

    // prologue: stage tile 0 into buf 0
    GLD16(kp + gk0, &Ks[0][l0]); GLD16(kp + gk1, &Ks[0][l1]);
    GLD16(vp + gv0, &Vs[0][l0]); GLD16(vp + gv1, &Vs[0][l1]);
    kp += 4096; vp += 64;
    WAIT_VM0();
    BAR();

    int cur = 0;
    for (int tile = 0; tile < 16; ++tile) {
        if (tile < 15) {   // stage next tile (stays in flight through compute)
            GLD16(kp + gk0, &Ks[cur ^ 1][l0]); GLD16(kp + gk1, &Ks[cur ^ 1][l1]);
            GLD16(vp + gv0, &Vs[cur ^ 1][l0]); GLD16(vp + gv1, &Vs[cur ^ 1][l1]);
            kp += 4096; vp += 64;
        }

        // S^T = K Q^T : sacc[cf][rr] = S[kv = cf*16+lg*4+rr][q = lr]
        f32x4 sacc[4] = {};
#pragma unroll
        for (int cf = 0; cf < 4; ++cf) {
            bf16x8 kf0 = *(const bf16x8*)(Ks[cur] + koff[cf]);
            sacc[cf] = __builtin_amdgcn_mfma_f32_16x16x32_bf16(kf0, qf[0], sacc[cf], 0, 0, 0);
            bf16x8 kf1 = *(const bf16x8*)(Ks[cur] + (koff[cf] ^ 32));
            sacc[cf] = __builtin_amdgcn_mfma_f32_16x16x32_bf16(kf1, qf[1], sacc[cf], 0, 0, 0);
        }

        // row max: in-register tree + 2 shfl (xor16, xor32)
        float rm;
        {
            float a0 = fmaxf(fmaxf(sacc[0][0], sacc[0][1]), fmaxf(sacc[0][2], sacc[0][3]));
            float a1 = fmaxf(fmaxf(sacc[1][0], sacc[1][1]), fmaxf(sacc[1][2], sacc[1][3]));
            float a2 = fmaxf(fmaxf(sacc[2][0], sacc[2][1]), fmaxf(sacc[2][2], sacc[2][3]));
            float a3 = fmaxf(fmaxf(sacc[3][0], sacc[3][1]), fmaxf(sacc[3][2], sacc[3][3]));
            rm = fmaxf(fmaxf(a0, a1), fmaxf(a2, a3));
        }
        rm = fmaxf(rm, __shfl_xor(rm, 16, 64));
        rm = fmaxf(rm, __shfl_xor(rm, 32, 64));
        rm *= LOG2E;

        if (__any(rm > m2)) {          // rescale only when some row's max grew
            float nm = fmaxf(m2, rm);
            float sc = exp2f(m2 - nm);
            m2 = nm;
            lsum *= sc;
            float scB[4];
#pragma unroll
            for (int rr = 0; rr < 4; ++rr)
                scB[rr] = __shfl(sc, (ln & 48) | (lg * 4 + rr), 64);
#pragma unroll
            for (int df = 0; df < 4; ++df)
#pragma unroll
                for (int rr = 0; rr < 4; ++rr) cacc[df][rr] *= scB[rr];
        }

        // p = exp2(s*log2e - m2); pack pairs -> 8 ds_write_b32, XOR-swizzled
        float p[4][4];
#pragma unroll
        for (int cf = 0; cf < 4; ++cf)
#pragma unroll
            for (int rr = 0; rr < 4; ++rr)
                p[cf][rr] = exp2f(fmaf(sacc[cf][rr], LOG2E, -m2));
#pragma unroll
        for (int cf = 0; cf < 4; ++cf) {
            Ps32[pwB + ((cf * 8 + lg * 2 + 0) ^ pxr)] =
                (unsigned)f2bf(p[cf][0]) | ((unsigned)f2bf(p[cf][1]) << 16);
            Ps32[pwB + ((cf * 8 + lg * 2 + 1) ^ pxr)] =
                (unsigned)f2bf(p[cf][2]) | ((unsigned)f2bf(p[cf][3]) << 16);
        }

        // row sum while the writes drain
        float rs;
        {
            float s0 = (p[0][0] + p[0][1]) + (p[0][2] + p[0][3]);
            float s1 = (p[1][0] + p[1][1]) + (p[1][2] + p[1][3]);
            float s2 = (p[2][0] + p[2][1]) + (p[2][2] + p[2][3]);
            float s3 = (p[3][0] + p[3][1]) + (p[3][2] + p[3][3]);
            rs = (s0 + s1) + (s2 + s3);
        }
        rs += __shfl_xor(rs, 16, 64);
        rs += __shfl_xor(rs, 32, 64);
        lsum += rs;

        WAIT_LGKM0();                  // P visible to own wave (no barrier)

        // ctx += P V
#pragma unroll
        for (int kvs = 0; kvs < 2; ++kvs) {
            bf16x8 pf = *(const bf16x8*)((const unsigned short*)Ps32 + (kvs ? prq1 : prq0));
#pragma unroll
            for (int df = 0; df < 4; ++df) {
                bf16x8 vf = *(const bf16x8*)(Vs[cur] + (koff[df] ^ (kvs * 32)));
                cacc[df] = __builtin_amdgcn_mfma_f32_16x16x32_bf16(pf, vf, cacc[df], 0, 0, 0);
            }
        }
        WAIT_VM0();                    // next tile's staging complete
        BAR();                         // all waves done reading buf[cur]
        cur ^= 1;
    }

    // epilogue: unnormalized partial ctx (bf16) + per-row m2/lsum
    size_t rbase = (size_t)bh * 1024 + q0 + wv * 16;
    unsigned short* pc = pctx + ((size_t)ch * 32768 + rbase) * 64;
#pragma unroll
    for (int df = 0; df < 4; ++df)
#pragma unroll
        for (int rr = 0; rr < 4; ++rr)
            pc[(lg * 4 + rr) * 64 + df * 16 + lr] = f2bf(cacc[df][rr]);
    if (lg == 0) {
        size_t idx = (size_t)ch * 32768 + rbase + lr;
        pm[idx] = m2;
        pl[idx] = lsum;
    }
}

// ---------------------------------------------------------------------------
// combine 2 kv-chunks: ctx = (c0*2^(m0-M) + c1*2^(m1-M)) / L, M=max, L=Σl·2^..
// 8 threads per row (8 d each); also emits m2 (log2 domain) and 1/L.
// ---------------------------------------------------------------------------
__global__ __launch_bounds__(256)
void combine_flash(const unsigned short* __restrict__ pctx,
                   const float* __restrict__ pm, const float* __restrict__ pl,
                   unsigned short* __restrict__ ctxb,
                   float* __restrict__ m2Out, float* __restrict__ linvOut)
{
    int gid = blockIdx.x * 256 + threadIdx.x;   // 262144
    int r = gid >> 3, dg = (gid & 7) * 8;
    float m0 = pm[r], m1 = pm[32768 + r];
    float l0 = pl[r], l1 = pl[32768 + r];
    float M = fmaxf(m0, m1);
    float s0 = exp2f(m0 - M), s1 = exp2f(m1 - M);
    float L = fmaf(l0, s0, l1 * s1);
    float linv = 1.f / L;
    float f0 = s0 * linv, f1 = s1 * linv;
    u16x8 a = *(const u16x8*)(pctx + (size_t)r * 64 + dg);
    u16x8 b = *(const u16x8*)(pctx + (size_t)(32768 + r) * 64 + dg);
    u16x8 o;
#pragma unroll
    for (int j = 0; j < 8; ++j)
        o[j] = f2bf(fmaf(bf2f(a[j]), f0, bf2f(b[j]) * f1));
    int bb = r >> 14, h = (r >> 10) & 15, q = r & 1023;
    *(u16x8*)(ctxb + ((size_t)(bb * 1024) + q) * 1024 + h * 64 + dg) = o;
    if (dg == 0) { m2Out[r] = M; linvOut[r] = linv; }
}

// ---------------------------------------------------------------------------
// attn-mean: block per (b, 64q, 64kv); loops 16 heads with double-buffered
// K staging. S by MFMA identical to flash.
// ---------------------------------------------------------------------------
__global__ __launch_bounds__(256)
void attn_mean_mfma(const unsigned short* __restrict__ Q,
                    const unsigned short* __restrict__ K,
                    const float* __restrict__ m2In, const float* __restrict__ linvIn,
                    float* __restrict__ attnOut)
{
    __shared__ unsigned short Ks[2][64 * 64];
    const int t  = threadIdx.x;
    const int wv = t >> 6, ln = t & 63;
    const int lr = ln & 15, lg = ln >> 4;
    const int kt = blockIdx.x, qt = blockIdx.y, b = blockIdx.z;
    const int q0 = qt * 64, kv0 = kt * 64;

    const int i0 = t, i1 = 256 + t;
    const int r0 = i0 >> 3, c0 = i0 & 7, sw0 = (c0 ^ (r0 & 7)) * 8;
    const int r1 = i1 >> 3, c1 = i1 & 7, sw1 = (c1 ^ (r1 & 7)) * 8;
    const int l0 = i0 * 8, l1 = i1 * 8;
    const int gk0 = r0 * 64 + sw0, gk1 = r1 * 64 + sw1;

    int koff[4];
#pragma unroll
    for (int cf = 0; cf < 4; ++cf)
        koff[cf] = (cf * 16 + lr) * 64 + ((lg ^ (lr & 7)) * 8);

    const unsigned short* kp = K + ((size_t)(b * 16) * 2048 + kv0) * 64;
    const unsigned short* qp = Q + ((size_t)(b * 16) * 1024 + q0 + wv * 16 + lr) * 64 + lg * 8;
    size_t ridx = (size_t)(b * 16) * 1024 + q0 + wv * 16 + lg * 4;

    float att[4][4] = {};

    // prologue: stage head 0
    GLD16(kp + gk0, &Ks[0][l0]); GLD16(kp + gk1, &Ks[0][l1]);
    kp += 131072;
    WAIT_VM0();
    BAR();

    int cur = 0;
    for (int h = 0; h < 16; ++h) {
        if (h < 15) {
            GLD16(kp + gk0, &Ks[cur ^ 1][l0]); GLD16(kp + gk1, &Ks[cur ^ 1][l1]);
            kp += 131072;
        }
        bf16x8 qf0 = *(const bf16x8*)qp;
        bf16x8 qf1 = *(const bf16x8*)(qp + 32);
        qp += 65536;
        float m2r[4], lir[4];
#pragma unroll
        for (int rr = 0; rr < 4; ++rr) {
            m2r[rr] = m2In[ridx + rr];
            lir[rr] = linvIn[ridx + rr];
        }
        ridx += 1024;

        f32x4 sacc[4] = {};
#pragma unroll
        for (int cf = 0; cf < 4; ++cf) {
            bf16x8 kf0 = *(const bf16x8*)(Ks[cur] + koff[cf]);
            sacc[cf] = __builtin_amdgcn_mfma_f32_16x16x32_bf16(qf0, kf0, sacc[cf], 0, 0, 0);
            bf16x8 kf1 = *(const bf16x8*)(Ks[cur] + (koff[cf] ^ 32));
            sacc[cf] = __builtin_amdgcn_mfma_f32_16x16x32_bf16(qf1, kf1, sacc[cf], 0, 0, 0);
        }
#pragma unroll
        for (int cf = 0; cf < 4; ++cf)
#pragma unroll
            for (int rr = 0; rr < 4; ++rr)
                att[cf][rr] += exp2f(sacc[cf][rr] * LOG2E - m2r[rr]) * lir[rr];

        WAIT_VM0();    // next head's K staged
        BAR();         // all waves done reading Ks[cur]
        cur ^= 1;
    }

#pragma unroll
    for (int cf = 0; cf < 4; ++cf)
#pragma unroll
        for (int rr = 0; rr < 4; ++rr) {
            int row = q0 + wv * 16 + lg * 4 + rr;
            int col = kv0 + cf * 16 + lr;
            attnOut[((size_t)b * 1024 + row) * 2048 + col] = att[cf][rr] * 0.0625f;
        }
}

// ---------------------------------------------------------------------------
// launch
// ---------------------------------------------------------------------------
extern "C" void kernel_launch(void* const* d_in, const int* in_sizes, int n_in,
                              void* d_out, int out_size, void* d_ws, size_t ws_size,
                              hipStream_t stream)
{
    const float* x_cond  = (const float*)d_in[0];
    const float* x_query = (const float*)d_in[1];
    const float* tok     = (const float*)d_in[2];
    const float* w_in    = (const float*)d_in[3];
    const float* b_in    = (const float*)d_in[4];
    const float* w_out   = (const float*)d_in[5];
    const float* b_out   = (const float*)d_in[6];

    float* fused = (float*)d_out;
    float* attn  = (float*)d_out + 2097152;

    unsigned short* ws = (unsigned short*)d_ws;
    unsigned short* Aq   = ws;              // 2M halves (dead after gemm_qkv)
    unsigned short* Ac   = Aq   + 2097152;  // 4M halves (dead after gemm_qkv)
    unsigned short* Wb   = Ac   + 4194304;  // 4M (wq,wk,wv,wo rows)
    unsigned short* Qh   = Wb   + 4194304;  // 2M
    unsigned short* Kh   = Qh   + 2097152;  // 4M
    unsigned short* Vh   = Kh   + 4194304;  // 4M
    unsigned short* Vt   = Vh   + 4194304;  // 4M
    unsigned short* ctxb = Vt   + 4194304;  // 2M
    float* m2b = (float*)(ctxb + 2097152);  // 32768
    float* lib = m2b + 32768;               // 32768

    // flash partials reuse the dead Aq/Ac region (gemm_qkv completes first):
    // pctx [2][32768][64] bf16 = 4,194,304 halves; pm/pl 65536 f32 each.
    unsigned short* pctx = ws;
    float* pmb = (float*)(ws + 4194304);
    float* plb = pmb + 65536;

    // 1. bf16 conversions (tok[1] -> query, tok[0] -> cond)
    conv_bf16<<<1024, 256, 0, stream>>>(x_query, tok + 1024, Aq, 262144);
    conv_bf16<<<2048, 256, 0, stream>>>(x_cond,  tok,        Ac, 524288);
    conv_bf16<<<1536, 256, 0, stream>>>(w_in,  nullptr, Wb,           393216);
    conv_bf16<<< 512, 256, 0, stream>>>(w_out, nullptr, Wb + 3145728, 131072);

    // 2. merged Q/K/V projection (Q scaled by 0.125, folded)
    gemm_qkv<<<dim3(8, 80), 256, 0, stream>>>(Aq, Ac, Wb, b_in, Qh, Kh, Vh);

    // 3. V transpose -> [bh][64][2048]
    transpose_v<<<dim3(32, 32), 256, 0, stream>>>(Vh, Vt);

    // 4. attention: chunked flash -> combine -> mean
    flash_fwd<<<dim3(16, 2, 32), 256, 0, stream>>>(Qh, Kh, Vt, pctx, pmb, plb);
    combine_flash<<<1024, 256, 0, stream>>>(pctx, pmb, plb, ctxb, m2b, lib);
    attn_mean_mfma<<<dim3(32, 16, 2), 256, 0, stream>>>(Qh, Kh, m2b, lib, attn);

    // 5. output projection (f32 out)
    gemm_mfma<<<dim3(8, 16), 256, 0, stream>>>(ctxb, Wb + 3145728, b_out, fused);
}

// Round 9
// 238.741 us; speedup vs baseline: 16.6021x; 1.0492x over previous
//
#include <hip/hip_runtime.h>
#include <hip/hip_bf16.h>
#include <cstddef>
#include <cstdint>

// B=2, Lq=1024, Lkv=2048, D=1024, H=16, hd=64.  All MFMA = 16x16x32 bf16.

typedef float  f32x4  __attribute__((ext_vector_type(4)));
typedef short  bf16x8 __attribute__((ext_vector_type(8)));
typedef unsigned short u16x8 __attribute__((ext_vector_type(8)));
typedef __attribute__((address_space(1))) const void gvoid;
typedef __attribute__((address_space(3))) void lvoid;
#define GLD16(g, l) __builtin_amdgcn_global_load_lds((gvoid*)(g), (lvoid*)(l), 16, 0, 0)
#define WAIT_VM0()   asm volatile("s_waitcnt vmcnt(0)" ::: "memory")
#define WAIT_LGKM0() asm volatile("s_waitcnt lgkmcnt(0)" ::: "memory")
#define BAR() __builtin_amdgcn_s_barrier()
#define LOG2E 1.4426950408889634f

static __device__ __forceinline__ unsigned short f2bf(float f) {
    union { float f; unsigned u; } v; v.f = f;
    unsigned r = v.u + 0x7fff + ((v.u >> 16) & 1);   // RNE
    return (unsigned short)(r >> 16);
}
static __device__ __forceinline__ float bf2f(unsigned short u) {
    union { unsigned u; float f; } v; v.u = (unsigned)u << 16; return v.f;
}
// native packed f32x2 -> bf16x2 (RNE on gfx950)
static __device__ __forceinline__ unsigned cvtpk(float lo, float hi) {
    unsigned r;
    asm("v_cvt_pk_bf16_f32 %0, %1, %2" : "=v"(r) : "v"(lo), "v"(hi));
    return r;
}

// ---------------------------------------------------------------------------
// merged conversions: all 4 f32->bf16 segments in one dispatch.
// 1,310,720 items x 8 elems.  tok col = (off*8) & 1023.
// ---------------------------------------------------------------------------
__global__ __launch_bounds__(256)
void conv_all(const float* __restrict__ xq, const float* __restrict__ xc,
              const float* __restrict__ tok,
              const float* __restrict__ w_in, const float* __restrict__ w_out,
              unsigned short* __restrict__ Aq, unsigned short* __restrict__ Ac,
              unsigned short* __restrict__ Wb)
{
    int i = blockIdx.x * 256 + threadIdx.x;
    const float* src; const float* tokp = nullptr;
    unsigned short* dst; int off;
    if (i < 262144)       { src = xq;    tokp = tok + 1024; dst = Aq;            off = i; }
    else if (i < 786432)  { src = xc;    tokp = tok;        dst = Ac;            off = i - 262144; }
    else if (i < 1179648) { src = w_in;                     dst = Wb;            off = i - 786432; }
    else                  { src = w_out;                    dst = Wb + 3145728;  off = i - 1179648; }

    const float4* sp = (const float4*)src + (size_t)off * 2;
    float4 a = sp[0], b = sp[1];
    if (tokp) {
        int col = (off * 8) & 1023;
        const float4* tp = (const float4*)(tokp + col);
        float4 t0 = tp[0], t1 = tp[1];
        a.x += t0.x; a.y += t0.y; a.z += t0.z; a.w += t0.w;
        b.x += t1.x; b.y += t1.y; b.z += t1.z; b.w += t1.w;
    }
    u16x8 r;
    r[0] = f2bf(a.x); r[1] = f2bf(a.y); r[2] = f2bf(a.z); r[3] = f2bf(a.w);
    r[4] = f2bf(b.x); r[5] = f2bf(b.y); r[6] = f2bf(b.z); r[7] = f2bf(b.w);
    ((u16x8*)dst)[off] = r;
}

// ---------------------------------------------------------------------------
// Merged QKV MFMA GEMM: one dispatch, grid (8, 80): y<16 Q, y<48 K, else V.
// 128x128 tile, BK=64, m97-structure (single-buffer).  (unchanged)
// ---------------------------------------------------------------------------
__global__ __launch_bounds__(256)
void gemm_qkv(const unsigned short* __restrict__ Aq,
              const unsigned short* __restrict__ Ac,
              const unsigned short* __restrict__ W,
              const float* __restrict__ bias,
              unsigned short* __restrict__ Qh,
              unsigned short* __restrict__ Kh,
              unsigned short* __restrict__ Vh)
{
    __shared__ unsigned short As[128 * 64];
    __shared__ unsigned short Bs[128 * 64];
    const int t  = threadIdx.x;
    const int wv = t >> 6, ln = t & 63;
    const int wr = wv >> 1, wc = wv & 1;
    const int lr = ln & 15, lg = ln >> 4;
    const int y = blockIdx.y;

    const unsigned short* A; const unsigned short* Wp; const float* bs;
    unsigned short* Y; int Lshift, m0; float scale;
    if (y < 16)      { A = Aq; m0 = y * 128;        Wp = W;           bs = bias;        Y = Qh; Lshift = 10; scale = 0.125f; }
    else if (y < 48) { A = Ac; m0 = (y - 16) * 128; Wp = W + 1048576; bs = bias + 1024; Y = Kh; Lshift = 11; scale = 1.0f; }
    else             { A = Ac; m0 = (y - 48) * 128; Wp = W + 2097152; bs = bias + 2048; Y = Vh; Lshift = 11; scale = 1.0f; }
    const int n0 = blockIdx.x * 128;

    f32x4 acc[4][4] = {};

    for (int k0 = 0; k0 < 1024; k0 += 64) {
        __syncthreads();
#pragma unroll
        for (int ia = 0; ia < 4; ++ia) {
            int idx = ia * 256 + t;
            int row = idx >> 3, c = idx & 7;
            int sw = (c ^ (row & 7)) * 8;
            GLD16(A  + (size_t)(m0 + row) * 1024 + k0 + sw, As + idx * 8);
            GLD16(Wp + (size_t)(n0 + row) * 1024 + k0 + sw, Bs + idx * 8);
        }
        WAIT_VM0();
        __syncthreads();
#pragma unroll
        for (int ks = 0; ks < 2; ++ks) {
            bf16x8 af[4], bf[4];
#pragma unroll
            for (int i = 0; i < 4; ++i) {
                int rowA = wr * 64 + i * 16 + lr;
                af[i] = *(const bf16x8*)(As + rowA * 64 + (((ks * 4 + lg) ^ (rowA & 7)) * 8));
                int rowB = wc * 64 + i * 16 + lr;
                bf[i] = *(const bf16x8*)(Bs + rowB * 64 + (((ks * 4 + lg) ^ (rowB & 7)) * 8));
            }
#pragma unroll
            for (int i = 0; i < 4; ++i)
#pragma unroll
                for (int j = 0; j < 4; ++j)
                    acc[i][j] = __builtin_amdgcn_mfma_f32_16x16x32_bf16(af[i], bf[j], acc[i][j], 0, 0, 0);
        }
    }

#pragma unroll
    for (int i = 0; i < 4; ++i) {
        int rb = m0 + wr * 64 + i * 16 + lg * 4;
#pragma unroll
        for (int j = 0; j < 4; ++j) {
            int col = n0 + wc * 64 + j * 16 + lr;
            float bv = bs[col];
#pragma unroll
            for (int rr = 0; rr < 4; ++rr) {
                float v = (acc[i][j][rr] + bv) * scale;
                int r = rb + rr;
                int b = r >> Lshift, l = r & ((1 << Lshift) - 1);
                int hh = col >> 6, d = col & 63;
                Y[((((size_t)b * 16 + hh) << Lshift) + l) * 64 + d] = f2bf(v);
            }
        }
    }
}

// ---------------------------------------------------------------------------
// Out-projection GEMM: 64x128 tile -> grid (8,32) = 256 blocks (1/CU),
// 2-phase double-buffered staging (drain overlapped with compute).
// ---------------------------------------------------------------------------
__global__ __launch_bounds__(256)
void gemm_out(const unsigned short* __restrict__ A,
              const unsigned short* __restrict__ W,
              const float* __restrict__ bias,
              float* __restrict__ Y)
{
    __shared__ unsigned short As[2][64 * 64];
    __shared__ unsigned short Bs[2][128 * 64];
    const int t  = threadIdx.x;
    const int wv = t >> 6, ln = t & 63;
    const int wr = wv >> 1, wc = wv & 1;
    const int lr = ln & 15, lg = ln >> 4;
    const int m0 = blockIdx.y * 64, n0 = blockIdx.x * 128;

    // staging maps (chunks of 8 halves)
    const int rA0 = (0 * 256 + t) >> 3, cA0 = t & 7, swA0 = (cA0 ^ (rA0 & 7)) * 8;
    const int rA1 = (1 * 256 + t) >> 3, cA1 = t & 7, swA1 = (cA1 ^ (rA1 & 7)) * 8;

    f32x4 acc[2][4] = {};

#define STAGE_OUT(k0, buf)                                                          \
    do {                                                                            \
        GLD16(A + (size_t)(m0 + rA0) * 1024 + (k0) + swA0, &As[buf][(0 * 256 + t) * 8]); \
        GLD16(A + (size_t)(m0 + rA1) * 1024 + (k0) + swA1, &As[buf][(1 * 256 + t) * 8]); \
        _Pragma("unroll")                                                           \
        for (int ia = 0; ia < 4; ++ia) {                                            \
            int idx = ia * 256 + t;                                                 \
            int row = idx >> 3, c = idx & 7;                                        \
            int sw = (c ^ (row & 7)) * 8;                                           \
            GLD16(W + (size_t)(n0 + row) * 1024 + (k0) + sw, &Bs[buf][idx * 8]);    \
        }                                                                           \
    } while (0)

    STAGE_OUT(0, 0);
    WAIT_VM0();
    __syncthreads();

    int cur = 0;
    for (int kt = 0; kt < 16; ++kt) {
        if (kt < 15) STAGE_OUT((kt + 1) * 64, cur ^ 1);
#pragma unroll
        for (int ks = 0; ks < 2; ++ks) {
            bf16x8 af[2], bf[4];
#pragma unroll
            for (int i = 0; i < 2; ++i) {
                int rowA = wr * 32 + i * 16 + lr;
                af[i] = *(const bf16x8*)(&As[cur][0] + rowA * 64 + (((ks * 4 + lg) ^ (rowA & 7)) * 8));
            }
#pragma unroll
            for (int j = 0; j < 4; ++j) {
                int rowB = wc * 64 + j * 16 + lr;
                bf[j] = *(const bf16x8*)(&Bs[cur][0] + rowB * 64 + (((ks * 4 + lg) ^ (rowB & 7)) * 8));
            }
#pragma unroll
            for (int i = 0; i < 2; ++i)
#pragma unroll
                for (int j = 0; j < 4; ++j)
                    acc[i][j] = __builtin_amdgcn_mfma_f32_16x16x32_bf16(af[i], bf[j], acc[i][j], 0, 0, 0);
        }
        WAIT_VM0();
        __syncthreads();
        cur ^= 1;
    }
#undef STAGE_OUT

#pragma unroll
    for (int i = 0; i < 2; ++i) {
        int rb = m0 + wr * 32 + i * 16 + lg * 4;
#pragma unroll
        for (int j = 0; j < 4; ++j) {
            int col = n0 + wc * 64 + j * 16 + lr;
            float bv = bias[col];
#pragma unroll
            for (int rr = 0; rr < 4; ++rr)
                Y[(size_t)(rb + rr) * 1024 + col] = acc[i][j][rr] + bv;
        }
    }
}

// ---------------------------------------------------------------------------
// Vh[b][h][2048][64] -> Vt[b][h][64][2048]  (bf16 transpose via LDS)
// ---------------------------------------------------------------------------
__global__ __launch_bounds__(256)
void transpose_v(const unsigned short* __restrict__ Vh, unsigned short* __restrict__ Vt)
{
    __shared__ unsigned short L[64 * 72];
    const int t = threadIdx.x;
    const int kt = blockIdx.x;   // 0..31 kv tile
    const int bh = blockIdx.y;   // 0..31
    const unsigned short* src = Vh + ((size_t)bh * 2048 + kt * 64) * 64;
#pragma unroll
    for (int i = 0; i < 2; ++i) {
        int idx = i * 256 + t;
        int kv = idx >> 3, c = idx & 7;
        *(bf16x8*)(L + kv * 72 + c * 8) = *(const bf16x8*)(src + kv * 64 + c * 8);
    }
    __syncthreads();
#pragma unroll
    for (int i = 0; i < 2; ++i) {
        int idx = i * 256 + t;
        int d = idx >> 3, ck = idx & 7;
        u16x8 r;
#pragma unroll
        for (int j = 0; j < 8; ++j) r[j] = L[(ck * 8 + j) * 72 + d];
        *(u16x8*)(Vt + ((size_t)bh * 64 + d) * 2048 + kt * 64 + ck * 8) = r;
    }
}

// ---------------------------------------------------------------------------
// Flash attention, swapped QK^T, KV-split C=2.  cvt_pk P-pack (T12),
// max3-shaped row max (T17).  Grid 1024 blocks; LDS 40960 B.
// ---------------------------------------------------------------------------
__global__ __launch_bounds__(256)
void flash_fwd(const unsigned short* __restrict__ Q,
               const unsigned short* __restrict__ K,
               const unsigned short* __restrict__ Vt,
               unsigned short* __restrict__ pctx,   // [2][32768][64] bf16
               float* __restrict__ pm,              // [2][32768]
               float* __restrict__ pl)              // [2][32768]
{
    __shared__ unsigned short Ks[2][4096];
    __shared__ unsigned short Vs[2][4096];
    __shared__ unsigned int   Ps32[64 * 32];   // stride 32 u32/row, XOR-swizzled
    const int t  = threadIdx.x;
    const int wv = t >> 6, ln = t & 63;
    const int lr = ln & 15, lg = ln >> 4;
    const int qt = blockIdx.x, ch = blockIdx.y, bh = blockIdx.z;
    const int q0 = qt * 64;

    const int i0 = t, i1 = 256 + t;
    const int r0 = i0 >> 3, c0 = i0 & 7, sw0 = (c0 ^ (r0 & 7)) * 8;
    const int r1 = i1 >> 3, c1 = i1 & 7, sw1 = (c1 ^ (r1 & 7)) * 8;
    const int l0 = i0 * 8, l1 = i1 * 8;
    const int gk0 = r0 * 64 + sw0,   gk1 = r1 * 64 + sw1;
    const int gv0 = r0 * 2048 + sw0, gv1 = r1 * 2048 + sw1;

    int koff[4];
#pragma unroll
    for (int cf = 0; cf < 4; ++cf)
        koff[cf] = (cf * 16 + lr) * 64 + ((lg ^ (lr & 7)) * 8);
    const int pwB = (wv * 16 + lr) * 32;      // u32 row base (own row)
    const int pxr = (lr & 7) * 4;             // XOR key, u32-word domain
    const int prq0 = (wv * 16 + lr) * 64 + ((lg ^ (lr & 7)) * 8);        // kvs=0
    const int prq1 = (wv * 16 + lr) * 64 + (((4 + lg) ^ (lr & 7)) * 8);  // kvs=1

    bf16x8 qf[2];
    {
        const unsigned short* qp = Q + ((size_t)bh * 1024 + q0 + wv * 16 + lr) * 64 + lg * 8;
        qf[0] = *(const bf16x8*)qp;
        qf[1] = *(const bf16x8*)(qp + 32);
    }

    f32x4 cacc[4] = {};
    float m2 = -1e30f, lsum = 0.f;   // per-lane q row = q0 + wv*16 + lr

    const unsigned short* kp = K  + ((size_t)bh * 2048 + ch * 1024) * 64;
    const unsigned short* vp = Vt + (size_t)bh * 64 * 2048 + ch * 1024;

    GLD16(kp + gk0, &Ks[0][l0]); GLD16(kp + gk1, &Ks[0][l1]);
    GLD16(vp + gv0, &Vs[0][l0]); GLD16(vp + gv1, &Vs[0][l1]);
    kp += 4096; vp += 64;
    WAIT_VM0();
    BAR();

    int cur = 0;
    for (int tile = 0; tile < 16; ++tile) {
        if (tile < 15) {
            GLD16(kp + gk0, &Ks[cur ^ 1][l0]); GLD16(kp + gk1, &Ks[cur ^ 1][l1]);
            GLD16(vp + gv0, &Vs[cur ^ 1][l0]); GLD16(vp + gv1, &Vs[cur ^ 1][l1]);
            kp += 4096; vp += 64;
        }

        // S^T = K Q^T : sacc[cf][rr] = S[kv = cf*16+lg*4+rr][q = lr]
        f32x4 sacc[4] = {};
#pragma unroll
        for (int cf = 0; cf < 4; ++cf) {
            bf16x8 kf0 = *(const bf16x8*)(Ks[cur] + koff[cf]);
            sacc[cf] = __builtin_amdgcn_mfma_f32_16x16x32_bf16(kf0, qf[0], sacc[cf], 0, 0, 0);
            bf16x8 kf1 = *(const bf16x8*)(Ks[cur] + (koff[cf] ^ 32));
            sacc[cf] = __builtin_amdgcn_mfma_f32_16x16x32_bf16(kf1, qf[1], sacc[cf], 0, 0, 0);
        }

        // row max: max3-shaped tree + 2 shfl (xor16, xor32)
        float rm;
        {
            float a0 = fmaxf(fmaxf(sacc[0][0], sacc[0][1]), sacc[0][2]);
            float a1 = fmaxf(fmaxf(sacc[0][3], sacc[1][0]), sacc[1][1]);
            float a2 = fmaxf(fmaxf(sacc[1][2], sacc[1][3]), sacc[2][0]);
            float a3 = fmaxf(fmaxf(sacc[2][1], sacc[2][2]), sacc[2][3]);
            float a4 = fmaxf(fmaxf(sacc[3][0], sacc[3][1]), sacc[3][2]);
            rm = fmaxf(fmaxf(fmaxf(a0, a1), fmaxf(a2, a3)), fmaxf(a4, sacc[3][3]));
        }
        rm = fmaxf(rm, __shfl_xor(rm, 16, 64));
        rm = fmaxf(rm, __shfl_xor(rm, 32, 64));
        rm *= LOG2E;

        if (__any(rm > m2)) {
            float nm = fmaxf(m2, rm);
            float sc = exp2f(m2 - nm);
            m2 = nm;
            lsum *= sc;
            float scB[4];
#pragma unroll
            for (int rr = 0; rr < 4; ++rr)
                scB[rr] = __shfl(sc, (ln & 48) | (lg * 4 + rr), 64);
#pragma unroll
            for (int df = 0; df < 4; ++df)
#pragma unroll
                for (int rr = 0; rr < 4; ++rr) cacc[df][rr] *= scB[rr];
        }

        // p = exp2(s*log2e - m2); cvt_pk pack -> 8 ds_write_b32 (own rows)
        float p[4][4];
#pragma unroll
        for (int cf = 0; cf < 4; ++cf)
#pragma unroll
            for (int rr = 0; rr < 4; ++rr)
                p[cf][rr] = exp2f(fmaf(sacc[cf][rr], LOG2E, -m2));
#pragma unroll
        for (int cf = 0; cf < 4; ++cf) {
            Ps32[pwB + ((cf * 8 + lg * 2 + 0) ^ pxr)] = cvtpk(p[cf][0], p[cf][1]);
            Ps32[pwB + ((cf * 8 + lg * 2 + 1) ^ pxr)] = cvtpk(p[cf][2], p[cf][3]);
        }

        float rs;
        {
            float s0 = (p[0][0] + p[0][1]) + (p[0][2] + p[0][3]);
            float s1 = (p[1][0] + p[1][1]) + (p[1][2] + p[1][3]);
            float s2 = (p[2][0] + p[2][1]) + (p[2][2] + p[2][3]);
            float s3 = (p[3][0] + p[3][1]) + (p[3][2] + p[3][3]);
            rs = (s0 + s1) + (s2 + s3);
        }
        rs += __shfl_xor(rs, 16, 64);
        rs += __shfl_xor(rs, 32, 64);
        lsum += rs;

        WAIT_LGKM0();                  // P visible to own wave (no barrier)

        // ctx += P V
#pragma unroll
        for (int kvs = 0; kvs < 2; ++kvs) {
            bf16x8 pf = *(const bf16x8*)((const unsigned short*)Ps32 + (kvs ? prq1 : prq0));
#pragma unroll
            for (int df = 0; df < 4; ++df) {
                bf16x8 vf = *(const bf16x8*)(Vs[cur] + (koff[df] ^ (kvs * 32)));
                cacc[df] = __builtin_amdgcn_mfma_f32_16x16x32_bf16(pf, vf, cacc[df], 0, 0, 0);
            }
        }
        WAIT_VM0();
        BAR();
        cur ^= 1;
    }

    size_t rbase = (size_t)bh * 1024 + q0 + wv * 16;
    unsigned short* pc = pctx + ((size_t)ch * 32768 + rbase) * 64;
#pragma unroll
    for (int df = 0; df < 4; ++df)
#pragma unroll
        for (int rr = 0; rr < 4; ++rr)
            pc[(lg * 4 + rr) * 64 + df * 16 + lr] = f2bf(cacc[df][rr]);
    if (lg == 0) {
        size_t idx = (size_t)ch * 32768 + rbase + lr;
        pm[idx] = m2;
        pl[idx] = lsum;
    }
}

// ---------------------------------------------------------------------------
// combine 2 kv-chunks -> normalized ctx (bf16) + m2/linv
// ---------------------------------------------------------------------------
__global__ __launch_bounds__(256)
void combine_flash(const unsigned short* __restrict__ pctx,
                   const float* __restrict__ pm, const float* __restrict__ pl,
                   unsigned short* __restrict__ ctxb,
                   float* __restrict__ m2Out, float* __restrict__ linvOut)
{
    int gid = blockIdx.x * 256 + threadIdx.x;   // 262144
    int r = gid >> 3, dg = (gid & 7) * 8;
    float m0 = pm[r], m1 = pm[32768 + r];
    float l0 = pl[r], l1 = pl[32768 + r];
    float M = fmaxf(m0, m1);
    float s0 = exp2f(m0 - M), s1 = exp2f(m1 - M);
    float L = fmaf(l0, s0, l1 * s1);
    float linv = 1.f / L;
    float f0 = s0 * linv, f1 = s1 * linv;
    u16x8 a = *(const u16x8*)(pctx + (size_t)r * 64 + dg);
    u16x8 b = *(const u16x8*)(pctx + (size_t)(32768 + r) * 64 + dg);
    u16x8 o;
#pragma unroll
    for (int j = 0; j < 8; ++j)
        o[j] = f2bf(fmaf(bf2f(a[j]), f0, bf2f(b[j]) * f1));
    int bb = r >> 14, h = (r >> 10) & 15, q = r & 1023;
    *(u16x8*)(ctxb + ((size_t)(bb * 1024) + q) * 1024 + h * 64 + dg) = o;
    if (dg == 0) { m2Out[r] = M; linvOut[r] = linv; }
}

// ---------------------------------------------------------------------------
// attn-mean: block per (b, 64q, 64kv); loops 16 heads, dbuf K staging.
// ---------------------------------------------------------------------------
__global__ __launch_bounds__(256)
void attn_mean_mfma(const unsigned short* __restrict__ Q,
                    const unsigned short* __restrict__ K,
                    const float* __restrict__ m2In, const float* __restrict__ linvIn,
                    float* __restrict__ attnOut)
{
    __shared__ unsigned short Ks[2][64 * 64];
    const int t  = threadIdx.x;
    const int wv = t >> 6, ln = t & 63;
    const int lr = ln & 15, lg = ln >> 4;
    const int kt = blockIdx.x, qt = blockIdx.y, b = blockIdx.z;
    const int q0 = qt * 64, kv0 = kt * 64;

    const int i0 = t, i1 = 256 + t;
    const int r0 = i0 >> 3, c0 = i0 & 7, sw0 = (c0 ^ (r0 & 7)) * 8;
    const int r1 = i1 >> 3, c1 = i1 & 7, sw1 = (c1 ^ (r1 & 7)) * 8;
    const int l0 = i0 * 8, l1 = i1 * 8;
    const int gk0 = r0 * 64 + sw0, gk1 = r1 * 64 + sw1;

    int koff[4];
#pragma unroll
    for (int cf = 0; cf < 4; ++cf)
        koff[cf] = (cf * 16 + lr) * 64 + ((lg ^ (lr & 7)) * 8);

    const unsigned short* kp = K + ((size_t)(b * 16) * 2048 + kv0) * 64;
    const unsigned short* qp = Q + ((size_t)(b * 16) * 1024 + q0 + wv * 16 + lr) * 64 + lg * 8;
    size_t ridx = (size_t)(b * 16) * 1024 + q0 + wv * 16 + lg * 4;

    float att[4][4] = {};

    GLD16(kp + gk0, &Ks[0][l0]); GLD16(kp + gk1, &Ks[0][l1]);
    kp += 131072;
    WAIT_VM0();
    BAR();

    int cur = 0;
    for (int h = 0; h < 16; ++h) {
        if (h < 15) {
            GLD16(kp + gk0, &Ks[cur ^ 1][l0]); GLD16(kp + gk1, &Ks[cur ^ 1][l1]);
            kp += 131072;
        }
        bf16x8 qf0 = *(const bf16x8*)qp;
        bf16x8 qf1 = *(const bf16x8*)(qp + 32);
        qp += 65536;
        float m2r[4], lir[4];
#pragma unroll
        for (int rr = 0; rr < 4; ++rr) {
            m2r[rr] = m2In[ridx + rr];
            lir[rr] = linvIn[ridx + rr];
        }
        ridx += 1024;

        f32x4 sacc[4] = {};
#pragma unroll
        for (int cf = 0; cf < 4; ++cf) {
            bf16x8 kf0 = *(const bf16x8*)(Ks[cur] + koff[cf]);
            sacc[cf] = __builtin_amdgcn_mfma_f32_16x16x32_bf16(qf0, kf0, sacc[cf], 0, 0, 0);
            bf16x8 kf1 = *(const bf16x8*)(Ks[cur] + (koff[cf] ^ 32));
            sacc[cf] = __builtin_amdgcn_mfma_f32_16x16x32_bf16(qf1, kf1, sacc[cf], 0, 0, 0);
        }
#pragma unroll
        for (int cf = 0; cf < 4; ++cf)
#pragma unroll
            for (int rr = 0; rr < 4; ++rr)
                att[cf][rr] += exp2f(sacc[cf][rr] * LOG2E - m2r[rr]) * lir[rr];

        WAIT_VM0();
        BAR();
        cur ^= 1;
    }

#pragma unroll
    for (int cf = 0; cf < 4; ++cf)
#pragma unroll
        for (int rr = 0; rr < 4; ++rr) {
            int row = q0 + wv * 16 + lg * 4 + rr;
            int col = kv0 + cf * 16 + lr;
            attnOut[((size_t)b * 1024 + row) * 2048 + col] = att[cf][rr] * 0.0625f;
        }
}

// ---------------------------------------------------------------------------
// launch
// ---------------------------------------------------------------------------
extern "C" void kernel_launch(void* const* d_in, const int* in_sizes, int n_in,
                              void* d_out, int out_size, void* d_ws, size_t ws_size,
                              hipStream_t stream)
{
    const float* x_cond  = (const float*)d_in[0];
    const float* x_query = (const float*)d_in[1];
    const float* tok     = (const float*)d_in[2];
    const float* w_in    = (const float*)d_in[3];
    const float* b_in    = (const float*)d_in[4];
    const float* w_out   = (const float*)d_in[5];
    const float* b_out   = (const float*)d_in[6];

    float* fused = (float*)d_out;
    float* attn  = (float*)d_out + 2097152;

    unsigned short* ws = (unsigned short*)d_ws;
    unsigned short* Aq   = ws;              // 2M halves (dead after gemm_qkv)
    unsigned short* Ac   = Aq   + 2097152;  // 4M halves (dead after gemm_qkv)
    unsigned short* Wb   = Ac   + 4194304;  // 4M (wq,wk,wv,wo rows)
    unsigned short* Qh   = Wb   + 4194304;  // 2M
    unsigned short* Kh   = Qh   + 2097152;  // 4M
    unsigned short* Vh   = Kh   + 4194304;  // 4M
    unsigned short* Vt   = Vh   + 4194304;  // 4M
    unsigned short* ctxb = Vt   + 4194304;  // 2M
    float* m2b = (float*)(ctxb + 2097152);  // 32768
    float* lib = m2b + 32768;               // 32768

    // flash partials reuse the dead Aq/Ac region (gemm_qkv completes first)
    unsigned short* pctx = ws;
    float* pmb = (float*)(ws + 4194304);
    float* plb = pmb + 65536;

    // 1. all bf16 conversions in one dispatch
    conv_all<<<5120, 256, 0, stream>>>(x_query, x_cond, tok, w_in, w_out, Aq, Ac, Wb);

    // 2. merged Q/K/V projection (Q scaled by 0.125, folded)
    gemm_qkv<<<dim3(8, 80), 256, 0, stream>>>(Aq, Ac, Wb, b_in, Qh, Kh, Vh);

    // 3. V transpose -> [bh][64][2048]
    transpose_v<<<dim3(32, 32), 256, 0, stream>>>(Vh, Vt);

    // 4. attention: chunked flash -> combine -> mean
    flash_fwd<<<dim3(16, 2, 32), 256, 0, stream>>>(Qh, Kh, Vt, pctx, pmb, plb);
    combine_flash<<<1024, 256, 0, stream>>>(pctx, pmb, plb, ctxb, m2b, lib);
    attn_mean_mfma<<<dim3(32, 16, 2), 256, 0, stream>>>(Qh, Kh, m2b, lib, attn);

    // 5. output projection (64x128 tiles, 256 blocks, dbuf)
    gemm_out<<<dim3(8, 32), 256, 0, stream>>>(ctxb, Wb + 3145728, b_out, fused);
}